// Round 16
// baseline (1389.590 us; speedup 1.0000x reference)
//
#include <hip/hip_runtime.h>
#include <math.h>

#define N_OP_   200000
#define N_MACH_ 1000
#define N_JOB_  20000
#define E_OM_   1000000
#define E_JO_   200000
#define N_PAIRS_ 500000

// merged CSR layout; om machines split into 64 sub-buckets each (atomic decontention)
#define B_OM_ 0
#define B_MO_ 64000
#define B_JO_ 264000
#define B_OJ_ 464000
#define TOTC_ 484000
#define E_TOT_ 2400000

#define CDIV(a,b) (((a)+(b)-1)/(b))

typedef __attribute__((ext_vector_type(8))) short short8v;   // 8 x bf16
typedef __attribute__((ext_vector_type(4))) float f32x4;

__device__ __forceinline__ unsigned short f2bf(float f){
  unsigned int u = __float_as_uint(f);
  return (unsigned short)((u + 0x7fffu + ((u>>16)&1u)) >> 16);
}
__device__ __forceinline__ float bf2f(unsigned short h){
  return __uint_as_float(((unsigned int)h)<<16);
}

// ---------------- encode ----------------
template<int DIN>
__global__ __launch_bounds__(256) void encode_kernel(const float* __restrict__ x,
    const float* __restrict__ W, float* __restrict__ out, int N){
  __shared__ float sW[DIN*16];
  if (threadIdx.x < DIN*16) sW[threadIdx.x] = W[threadIdx.x];
  __syncthreads();
  int i = blockIdx.x*blockDim.x + threadIdx.x;
  if (i >= N) return;
  float xv[DIN];
#pragma unroll
  for (int k=0;k<DIN;k++) xv[k] = x[i*DIN+k];
#pragma unroll
  for (int j=0;j<16;j++){
    float h = 0.f;
#pragma unroll
    for (int k=0;k<DIN;k++) h = fmaf(xv[k], sW[k*16+j], h);
    float s, c;
    sincosf(h, &s, &c);
    out[(size_t)i*64 + j]      = s;
    out[(size_t)i*64 + 16 + j] = c;
  }
}

// ---------------- merged CSR build (om -> 64 sub-buckets/machine) ----------------
__device__ __forceinline__ int edge_cidx(int e,
    const int* __restrict__ eom_d, const int* __restrict__ emo_d,
    const int* __restrict__ ejo_d, const int* __restrict__ eoj_d){
  if (e < E_OM_)            return B_OM_ + eom_d[e]*64 + (e & 63);
  else if (e < 2*E_OM_)     return B_MO_ + emo_d[e - E_OM_];
  else if (e < 2*E_OM_+E_JO_) return B_JO_ + ejo_d[e - 2*E_OM_];
  else                      return B_OJ_ + eoj_d[e - 2*E_OM_ - E_JO_];
}
__device__ __forceinline__ int edge_src(int e,
    const int* __restrict__ eom_s, const int* __restrict__ emo_s,
    const int* __restrict__ ejo_s, const int* __restrict__ eoj_s){
  if (e < E_OM_)            return eom_s[e];
  else if (e < 2*E_OM_)     return emo_s[e - E_OM_];
  else if (e < 2*E_OM_+E_JO_) return ejo_s[e - 2*E_OM_];
  else                      return eoj_s[e - 2*E_OM_ - E_JO_];
}

__global__ __launch_bounds__(256) void hist_all_kernel(
    const int* __restrict__ eom_d, const int* __restrict__ emo_d,
    const int* __restrict__ ejo_d, const int* __restrict__ eoj_d,
    int* __restrict__ cnt){
  int gsz = gridDim.x*blockDim.x;
  int i0 = blockIdx.x*blockDim.x + threadIdx.x;
  for (int base = i0; base < E_TOT_; base += 8*gsz){
    int c[8]; bool act[8];
#pragma unroll
    for (int j=0;j<8;j++){
      int e = base + j*gsz;
      act[j] = (e < E_TOT_);
      if (act[j]) c[j] = edge_cidx(e, eom_d, emo_d, ejo_d, eoj_d);
    }
#pragma unroll
    for (int j=0;j<8;j++) if (act[j]) atomicAdd(&cnt[c[j]], 1);
  }
}

__global__ __launch_bounds__(256) void fill_all_kernel(
    const int* __restrict__ eom_s, const int* __restrict__ eom_d,
    const int* __restrict__ emo_s, const int* __restrict__ emo_d,
    const int* __restrict__ ejo_s, const int* __restrict__ ejo_d,
    const int* __restrict__ eoj_s, const int* __restrict__ eoj_d,
    int* __restrict__ cursor, int* __restrict__ elist){
  int gsz = gridDim.x*blockDim.x;
  int i0 = blockIdx.x*blockDim.x + threadIdx.x;
  for (int base = i0; base < E_TOT_; base += 8*gsz){
    int cidx[8], src[8]; bool act[8];
#pragma unroll
    for (int j=0;j<8;j++){
      int e = base + j*gsz;
      act[j] = (e < E_TOT_);
      if (act[j]){
        cidx[j] = edge_cidx(e, eom_d, emo_d, ejo_d, eoj_d);
        src[j]  = edge_src (e, eom_s, emo_s, ejo_s, eoj_s);
      }
    }
    int p[8];
#pragma unroll
    for (int j=0;j<8;j++) if (act[j]) p[j] = atomicAdd(&cursor[cidx[j]], 1);
#pragma unroll
    for (int j=0;j<8;j++) if (act[j]) elist[p[j]] = src[j];
  }
}

// scan over 2048 elements per block (TOTC_=484000 -> NB=237 <= 256)
__global__ void scan_block_sums(const int* __restrict__ cnt, int N, int* __restrict__ partials){
  __shared__ int red[256];
  int base = blockIdx.x*2048;
  int s = 0;
#pragma unroll
  for (int j=0;j<8;j++){ int i = base + threadIdx.x + j*256; if (i<N) s += cnt[i]; }
  red[threadIdx.x] = s; __syncthreads();
  for (int st=128; st>0; st>>=1){ if (threadIdx.x<st) red[threadIdx.x]+=red[threadIdx.x+st]; __syncthreads(); }
  if (threadIdx.x==0) partials[blockIdx.x] = red[0];
}

__global__ void scan_partials(int* __restrict__ partials, int NB, int* __restrict__ offN){
  __shared__ int buf[256];
  int v = (threadIdx.x < NB) ? partials[threadIdx.x] : 0;
  buf[threadIdx.x] = v; __syncthreads();
  int acc = v;
  for (int st=1; st<256; st<<=1){
    int t = (threadIdx.x >= st) ? buf[threadIdx.x-st] : 0;
    __syncthreads();
    acc += t; buf[threadIdx.x] = acc;
    __syncthreads();
  }
  if (threadIdx.x < NB) partials[threadIdx.x] = acc - v;  // exclusive
  if (threadIdx.x == NB-1) offN[0] = acc;                 // total
}

__global__ void scan_write_offsets(const int* __restrict__ cnt, int N,
    const int* __restrict__ partials, int* __restrict__ off){
  __shared__ int buf[256];
  int base = blockIdx.x*2048;
  int v[8]; int s = 0;
#pragma unroll
  for (int j=0;j<8;j++){ int i = base + threadIdx.x*8 + j; v[j] = (i<N)?cnt[i]:0; s += v[j]; }
  buf[threadIdx.x] = s; __syncthreads();
  int acc = s;
  for (int st=1; st<256; st<<=1){
    int t = (threadIdx.x >= st) ? buf[threadIdx.x-st] : 0;
    __syncthreads();
    acc += t; buf[threadIdx.x] = acc;
    __syncthreads();
  }
  int ex = partials[blockIdx.x] + acc - s;
#pragma unroll
  for (int j=0;j<8;j++){ int i = base + threadIdx.x*8 + j; if (i<N) off[i] = ex; ex += v[j]; }
}

// ---------------- machine aggregation (64 sub-buckets per machine; block per machine) ----------------
__global__ __launch_bounds__(256) void agg_block_kernel(const int* __restrict__ off,
    const int* __restrict__ srcs, const float* __restrict__ feat,
    float* __restrict__ outp, int Ndst, int D){
  __shared__ float red[4][64];
  int m = blockIdx.x;
  if (m >= Ndst) return;
  int g = threadIdx.x >> 6, lane = threadIdx.x & 63;
  int s = off[m*64], e = off[m*64 + 64];
  float acc = 0.f;
  for (int base = s + g*64; base < e; base += 256){
    int cnt = e - base; if (cnt > 64) cnt = 64;
    int r = (lane < cnt) ? srcs[base + lane] : 0;
    int i = 0;
    for (; i + 4 <= cnt; i += 4){
      int r0 = __shfl(r, i), r1 = __shfl(r, i+1), r2 = __shfl(r, i+2), r3 = __shfl(r, i+3);
      float v0 = feat[(size_t)r0*64 + lane];
      float v1 = feat[(size_t)r1*64 + lane];
      float v2 = feat[(size_t)r2*64 + lane];
      float v3 = feat[(size_t)r3*64 + lane];
      acc += (v0 + v1) + (v2 + v3);
    }
    for (; i < cnt; i++){
      int ri = __shfl(r, i);
      acc += feat[(size_t)ri*64 + lane];
    }
  }
  red[g][lane] = acc;
  __syncthreads();
  if (g==0 && lane<D)
    outp[(size_t)m*64+lane] = red[0][lane]+red[1][lane]+red[2][lane]+red[3][lane];
}

// ---------------- fused partA (MFMA bf16 hi/lo = ~fp32): seg0 reads pre-agg; seg1-3 CSR-gather ----------------
template<int K>
__global__ __launch_bounds__(256,3) void partA_fused_kernel(
    const int* __restrict__ off_all, const int* __restrict__ elist,
    const float* __restrict__ Xop, const float* __restrict__ Xma, const float* __restrict__ Xjb,
    float* hm, float* ho1, float* ho2, float* hj,
    const float* __restrict__ Wm, const float* __restrict__ Wa,
    const float* __restrict__ Wb, const float* __restrict__ Wj,
    const float* __restrict__ bm, const float* __restrict__ ba,
    const float* __restrict__ bb, const float* __restrict__ bj,
    float* __restrict__ lstats,
    const float* __restrict__ epsp, int ebase)
{
  constexpr int NF4 = K/16;   // float4s per thread quarter in gather phase
  __shared__ unsigned short sAh[64][72];  // bf16 hi of z
  __shared__ unsigned short sAl[64][72];  // bf16 lo of z
  __shared__ unsigned short sBh[64][72];  // bf16 hi of W^T: [col][k]
  __shared__ unsigned short sBl[64][72];  // bf16 lo of W^T
  __shared__ float sred[16][64];
  const int tid = threadIdx.x;
  const int lane = tid & 63, w = tid >> 6;
  const int l16 = lane & 15, l4 = lane >> 4;
  const int Tm = (N_MACH_+63)>>6, To = (N_OP_+63)>>6;
  int t = blockIdx.x;
  int seg, tile;
  if (t < Tm){ seg=0; tile=t; }
  else if (t < Tm+To){ seg=1; tile=t-Tm; }
  else if (t < Tm+2*To){ seg=2; tile=t-Tm-To; }
  else { seg=3; tile=t-Tm-2*To; }
  float* z            = seg==0?hm:seg==1?ho1:seg==2?ho2:hj;
  const float* x      = seg==0?Xma:seg==3?Xjb:Xop;
  const float* feat   = seg==0?Xop:seg==1?Xma:seg==2?Xjb:Xop;
  const float* W      = seg==0?Wm:seg==1?Wa:seg==2?Wb:Wj;
  const float* b      = seg==0?bm:seg==1?ba:seg==2?bb:bj;
  const int N         = seg==0?N_MACH_:seg==3?N_JOB_:N_OP_;
  const int* offs     = off_all + (seg==0?B_OM_:seg==1?B_MO_:seg==2?B_JO_:B_OJ_);
  float* st           = lstats + seg*128;
  const float e1 = 1.0f + epsp[ebase + seg];
  // stage W^T hi/lo (bf16 pair): sB*[c][k]
  for (int idx = tid; idx < K*16; idx += 256){
    int k = idx >> 4, c4 = (idx & 15)*4;
    float4 wv = *(const float4*)&W[(size_t)k*64 + c4];
    unsigned short h0 = f2bf(wv.x), h1 = f2bf(wv.y), h2 = f2bf(wv.z), h3 = f2bf(wv.w);
    sBh[c4+0][k] = h0; sBl[c4+0][k] = f2bf(wv.x - bf2f(h0));
    sBh[c4+1][k] = h1; sBl[c4+1][k] = f2bf(wv.y - bf2f(h1));
    sBh[c4+2][k] = h2; sBl[c4+2][k] = f2bf(wv.z - bf2f(h2));
    sBh[c4+3][k] = h3; sBl[c4+3][k] = f2bf(wv.w - bf2f(h3));
  }
  const int rbase = tile << 6;
  // gather + pre-op (fp32), then split hi/lo into sA
  {
    const int r = tid >> 2, q = tid & 3;
    const int cbase = q*(K/4);
    int row = rbase + r;
    float4 a4[NF4];
#pragma unroll
    for (int f=0; f<NF4; f++) a4[f] = make_float4(0.f,0.f,0.f,0.f);
    if (row < N){
      if (seg == 0){
        const float4* H4 = (const float4*)&z[(size_t)row*64 + cbase];
#pragma unroll
        for (int f=0; f<NF4; f++) a4[f] = H4[f];
      } else {
        int s = offs[row], e = offs[row+1];
        int i = s;
        for (; i+2<=e; i+=2){
          int s0 = elist[i], s1 = elist[i+1];
          const float4* F0 = (const float4*)&feat[(size_t)s0*64 + cbase];
          const float4* F1 = (const float4*)&feat[(size_t)s1*64 + cbase];
          float4 v0[NF4], v1[NF4];
#pragma unroll
          for (int f=0; f<NF4; f++){ v0[f]=F0[f]; v1[f]=F1[f]; }
#pragma unroll
          for (int f=0; f<NF4; f++){
            a4[f].x += v0[f].x + v1[f].x;
            a4[f].y += v0[f].y + v1[f].y;
            a4[f].z += v0[f].z + v1[f].z;
            a4[f].w += v0[f].w + v1[f].w;
          }
        }
        if (i < e){
          int s0 = elist[i];
          const float4* F0 = (const float4*)&feat[(size_t)s0*64 + cbase];
#pragma unroll
          for (int f=0; f<NF4; f++){
            float4 v = F0[f];
            a4[f].x += v.x; a4[f].y += v.y; a4[f].z += v.z; a4[f].w += v.w;
          }
        }
      }
      const float4* X4 = (const float4*)&x[(size_t)row*64 + cbase];
#pragma unroll
      for (int f=0; f<NF4; f++){
        float4 xv = X4[f];
        a4[f].x = fmaf(e1, xv.x, a4[f].x);
        a4[f].y = fmaf(e1, xv.y, a4[f].y);
        a4[f].z = fmaf(e1, xv.z, a4[f].z);
        a4[f].w = fmaf(e1, xv.w, a4[f].w);
      }
    }
#pragma unroll
    for (int f=0; f<NF4; f++){
      unsigned short h0 = f2bf(a4[f].x), h1 = f2bf(a4[f].y), h2 = f2bf(a4[f].z), h3 = f2bf(a4[f].w);
      ushort4 uh = make_ushort4(h0, h1, h2, h3);
      ushort4 ul = make_ushort4(f2bf(a4[f].x - bf2f(h0)), f2bf(a4[f].y - bf2f(h1)),
                                f2bf(a4[f].z - bf2f(h2)), f2bf(a4[f].w - bf2f(h3)));
      *(ushort4*)&sAh[r][cbase + f*4] = uh;
      *(ushort4*)&sAl[r][cbase + f*4] = ul;
    }
  }
  __syncthreads();
  f32x4 acc[4];
#pragma unroll
  for (int n=0;n<4;n++) acc[n] = (f32x4){0.f,0.f,0.f,0.f};
  {
    short8v ah0 = *(const short8v*)&sAh[w*16 + l16][l4*8];
    short8v al0 = *(const short8v*)&sAl[w*16 + l16][l4*8];
#pragma unroll
    for (int n=0;n<4;n++){
      short8v bh0 = *(const short8v*)&sBh[n*16 + l16][l4*8];
      short8v bl0 = *(const short8v*)&sBl[n*16 + l16][l4*8];
      acc[n] = __builtin_amdgcn_mfma_f32_16x16x32_bf16(ah0, bh0, acc[n], 0, 0, 0);
      acc[n] = __builtin_amdgcn_mfma_f32_16x16x32_bf16(ah0, bl0, acc[n], 0, 0, 0);
      acc[n] = __builtin_amdgcn_mfma_f32_16x16x32_bf16(al0, bh0, acc[n], 0, 0, 0);
    }
    if (K == 64){
      short8v ah1 = *(const short8v*)&sAh[w*16 + l16][32 + l4*8];
      short8v al1 = *(const short8v*)&sAl[w*16 + l16][32 + l4*8];
#pragma unroll
      for (int n=0;n<4;n++){
        short8v bh1 = *(const short8v*)&sBh[n*16 + l16][32 + l4*8];
        short8v bl1 = *(const short8v*)&sBl[n*16 + l16][32 + l4*8];
        acc[n] = __builtin_amdgcn_mfma_f32_16x16x32_bf16(ah1, bh1, acc[n], 0, 0, 0);
        acc[n] = __builtin_amdgcn_mfma_f32_16x16x32_bf16(ah1, bl1, acc[n], 0, 0, 0);
        acc[n] = __builtin_amdgcn_mfma_f32_16x16x32_bf16(al1, bh1, acc[n], 0, 0, 0);
      }
    }
  }
  // epilogue: bias + store fp32 h1 + stats. D mapping: col = l16 (+16n), row = l4*4 + j.
  float ps[4] = {0.f,0.f,0.f,0.f};
  float pq[4] = {0.f,0.f,0.f,0.f};
#pragma unroll
  for (int n=0;n<4;n++){
    int col = n*16 + l16;
    float bv = b[col];
#pragma unroll
    for (int j=0;j<4;j++){
      int row = rbase + w*16 + l4*4 + j;
      if (row < N){
        float v = acc[n][j] + bv;
        z[(size_t)row*64 + col] = v;
        ps[n] += v; pq[n] += v*v;
      }
    }
  }
  __syncthreads();
#pragma unroll
  for (int n=0;n<4;n++) sred[w*4 + l4][n*16 + l16] = ps[n];
  __syncthreads();
  if (tid < 64){
    float s = 0.f;
#pragma unroll
    for (int j=0;j<16;j++) s += sred[j][tid];
    atomicAdd(&st[tid], s);
  }
  __syncthreads();
#pragma unroll
  for (int n=0;n<4;n++) sred[w*4 + l4][n*16 + l16] = pq[n];
  __syncthreads();
  if (tid < 64){
    float s = 0.f;
#pragma unroll
    for (int j=0;j<16;j++) s += sred[j][tid];
    atomicAdd(&st[64+tid], s);
  }
}

// ---------------- batched partB (MFMA bf16): 3 segments (mach, op-dual, job) ----------------
template<bool RESID>
__global__ __launch_bounds__(256,3) void partB_batch_kernel(
    float* h0, const float* x0, const float* W20, const float* b20, const float* sc0, int N0,
    float* hA, const float* hBp, const float* x1, const float* W2a, const float* W2b,
    const float* b2a_, const float* b2b_, const float* scA, const float* scB, int N1,
    float* h3, const float* x3, const float* W23, const float* b23, const float* sc3, int N3)
{
  __shared__ unsigned short sA[64][72];   // bf16 activations, padded
  __shared__ unsigned short sB[64][72];   // bf16 W^T: sB[col][k]
  const int tid = threadIdx.x;
  const int lane = tid & 63, w = tid >> 6;
  const int lo = lane & 15, hi = lane >> 4;
  const int T0=(N0+63)>>6, T1=(N1+63)>>6;
  int t = blockIdx.x;
  int seg, tile;
  if (t < T0){ seg=0; tile=t; }
  else if (t < T0+T1){ seg=1; tile=t-T0; }
  else { seg=2; tile=t-T0-T1; }
  const int N = seg==0?N0:seg==1?N1:N3;
  float* hout = seg==0?h0:seg==1?hA:h3;
  const float* x = seg==0?x0:seg==1?x1:x3;
  const int rbase = tile << 6;
  const int nsrc = (seg==1) ? 2 : 1;
  f32x4 acc[4];
#pragma unroll
  for (int n=0;n<4;n++) acc[n] = (f32x4){0.f,0.f,0.f,0.f};
  for (int s=0; s<nsrc; s++){
    const float* hsrc = (seg==1) ? (s==0? (const float*)hA : hBp)
                                 : (seg==0? (const float*)h0 : (const float*)h3);
    const float* Wp   = (seg==1) ? (s==0? W2a : W2b) : (seg==0? W20 : W23);
    const float* scp  = (seg==1) ? (s==0? scA : scB) : (seg==0? sc0 : sc3);
    __syncthreads();
    // stage W^T (bf16): sB[c][k]
    for (int idx = tid; idx < 1024; idx += 256){
      int k = idx >> 4, c4 = (idx & 15)*4;
      float4 wv = *(const float4*)&Wp[(size_t)k*64 + c4];
      sB[c4+0][k] = f2bf(wv.x);
      sB[c4+1][k] = f2bf(wv.y);
      sB[c4+2][k] = f2bf(wv.z);
      sB[c4+3][k] = f2bf(wv.w);
    }
    // stage A = relu(BN(h)) (bf16)
    for (int idx = tid; idx < 1024; idx += 256){
      int r = idx >> 4, c4 = (idx & 15)*4;
      int row = rbase + r;
      ushort4 zz = make_ushort4(0,0,0,0);
      if (row < N){
        float4 hv = *(const float4*)&hsrc[(size_t)row*64 + c4];
        float4 sc4 = *(const float4*)&scp[c4];
        float4 sh4 = *(const float4*)&scp[64 + c4];
        float a0 = fmaf(sc4.x, hv.x, sh4.x); a0 = a0>0.f?a0:0.f;
        float a1 = fmaf(sc4.y, hv.y, sh4.y); a1 = a1>0.f?a1:0.f;
        float a2 = fmaf(sc4.z, hv.z, sh4.z); a2 = a2>0.f?a2:0.f;
        float a3 = fmaf(sc4.w, hv.w, sh4.w); a3 = a3>0.f?a3:0.f;
        zz = make_ushort4(f2bf(a0), f2bf(a1), f2bf(a2), f2bf(a3));
      }
      *(ushort4*)&sA[r][c4] = zz;
    }
    __syncthreads();
    short8v af0 = *(const short8v*)&sA[w*16 + lo][hi*8];
    short8v af1 = *(const short8v*)&sA[w*16 + lo][32 + hi*8];
#pragma unroll
    for (int n=0;n<4;n++){
      short8v bf0 = *(const short8v*)&sB[n*16 + lo][hi*8];
      short8v bf1 = *(const short8v*)&sB[n*16 + lo][32 + hi*8];
      acc[n] = __builtin_amdgcn_mfma_f32_16x16x32_bf16(af0, bf0, acc[n], 0, 0, 0);
      acc[n] = __builtin_amdgcn_mfma_f32_16x16x32_bf16(af1, bf1, acc[n], 0, 0, 0);
    }
  }
  // epilogue: bias (+resid) + store. D mapping: col = lo (+16n), row = hi*4 + j.
#pragma unroll
  for (int n=0;n<4;n++){
    int col = n*16 + lo;
    float bv;
    if (seg==1) bv = b2a_[col] + b2b_[col];
    else if (seg==0) bv = b20[col];
    else bv = b23[col];
#pragma unroll
    for (int j=0;j<4;j++){
      int row = rbase + w*16 + hi*4 + j;
      if (row < N){
        float v = acc[n][j] + bv;
        if (RESID) v += x[(size_t)row*64 + col];
        hout[(size_t)row*64 + col] = v;
      }
    }
  }
}

// ---------------- fp1 (MFMA bf16): gather-GEMM (K=192) -> h1 bf16 + stats ----------------
__global__ __launch_bounds__(256,3) void fp1_gemm_kernel(
    const float* __restrict__ Xop, const float* __restrict__ Xma, const float* __restrict__ Xjb,
    const int* __restrict__ vpo, const int* __restrict__ vpm, const int* __restrict__ vpj,
    const float* __restrict__ Ws1, const float* __restrict__ bs1,
    unsigned short* __restrict__ h1bf,
    int P, float* __restrict__ gsum, float* __restrict__ gsq)
{
  __shared__ unsigned short sA[64][72];
  __shared__ unsigned short sB[64][72];
  __shared__ float sred[16][64];
  const int tid = threadIdx.x;
  const int lane = tid & 63, w = tid >> 6;
  const int lo = lane & 15, hi = lane >> 4;
  float ps[4] = {0.f,0.f,0.f,0.f};
  float pq[4] = {0.f,0.f,0.f,0.f};
  const int ntiles = (P + 63) >> 6;
  for (int t = blockIdx.x; t < ntiles; t += gridDim.x){
    const int rbase = t << 6;
    f32x4 acc[4];
#pragma unroll
    for (int n=0;n<4;n++) acc[n] = (f32x4){0.f,0.f,0.f,0.f};
    for (int s=0; s<3; s++){
      const int* vps = (s==0) ? vpo : (s==1) ? vpm : vpj;
      const float* Xs = (s==0) ? Xop : (s==1) ? Xma : Xjb;
      __syncthreads();
      // stage W chunk transposed (bf16)
      for (int idx = tid; idx < 1024; idx += 256){
        int k = idx >> 4, c4 = (idx & 15)*4;
        float4 wv = *(const float4*)&Ws1[(size_t)(s*64 + k)*64 + c4];
        sB[c4+0][k] = f2bf(wv.x);
        sB[c4+1][k] = f2bf(wv.y);
        sB[c4+2][k] = f2bf(wv.z);
        sB[c4+3][k] = f2bf(wv.w);
      }
      // stage gathered features (bf16)
      for (int idx = tid; idx < 1024; idx += 256){
        int r = idx >> 4, c4 = (idx & 15)*4;
        int row = rbase + r;
        ushort4 zz = make_ushort4(0,0,0,0);
        if (row < P){
          int nd = vps[row];
          float4 z = *(const float4*)&Xs[(size_t)nd*64 + c4];
          zz = make_ushort4(f2bf(z.x), f2bf(z.y), f2bf(z.z), f2bf(z.w));
        }
        *(ushort4*)&sA[r][c4] = zz;
      }
      __syncthreads();
      short8v af0 = *(const short8v*)&sA[w*16 + lo][hi*8];
      short8v af1 = *(const short8v*)&sA[w*16 + lo][32 + hi*8];
#pragma unroll
      for (int n=0;n<4;n++){
        short8v bf0 = *(const short8v*)&sB[n*16 + lo][hi*8];
        short8v bf1 = *(const short8v*)&sB[n*16 + lo][32 + hi*8];
        acc[n] = __builtin_amdgcn_mfma_f32_16x16x32_bf16(af0, bf0, acc[n], 0, 0, 0);
        acc[n] = __builtin_amdgcn_mfma_f32_16x16x32_bf16(af1, bf1, acc[n], 0, 0, 0);
      }
    }
    // epilogue: bias + store bf16 + stats
#pragma unroll
    for (int n=0;n<4;n++){
      int col = n*16 + lo;
      float bv = bs1[col];
#pragma unroll
      for (int j=0;j<4;j++){
        int row = rbase + w*16 + hi*4 + j;
        if (row < P){
          float v = acc[n][j] + bv;
          h1bf[(size_t)row*64 + col] = f2bf(v);
          ps[n] += v; pq[n] += v*v;
        }
      }
    }
  }
  // block reduction of per-lane column partials
  __syncthreads();
#pragma unroll
  for (int n=0;n<4;n++) sred[w*4 + hi][n*16 + lo] = ps[n];
  __syncthreads();
  if (tid < 64){
    float s = 0.f;
#pragma unroll
    for (int j=0;j<16;j++) s += sred[j][tid];
    atomicAdd(&gsum[tid], s);
  }
  __syncthreads();
#pragma unroll
  for (int n=0;n<4;n++) sred[w*4 + hi][n*16 + lo] = pq[n];
  __syncthreads();
  if (tid < 64){
    float s = 0.f;
#pragma unroll
    for (int j=0;j<16;j++) s += sred[j][tid];
    atomicAdd(&gsq[tid], s);
  }
}

// ---------------- fp2_lite: read bf16 h1, BN+ReLU, @Ws2+bs2 -> s2 (in place) + stats2 ----------------
__global__ __launch_bounds__(256,3) void fp2_lite_kernel(
    const float* __restrict__ scsh1,
    const float* __restrict__ Ws2, const float* __restrict__ bs2,
    const unsigned short* __restrict__ h1bf,
    float* __restrict__ s2out, int P,
    float* __restrict__ gsum2, float* __restrict__ gsq2)
{
  __shared__ float sZ[64][68];
  __shared__ float sW2[64][32];
  __shared__ float sred[16][64];
  const int tid = threadIdx.x;
  const int lc = tid & 15, lr = tid >> 4;
  for (int idx = tid*4; idx < 2048; idx += 1024){
    int k = idx >> 5, c = idx & 31;
    *(float4*)&sW2[k][c] = *(const float4*)&Ws2[(size_t)k*32 + c];
  }
  const float b2a = bs2[lc*2], b2b = bs2[lc*2+1];
  const int rbase = blockIdx.x << 6;
  for (int idx = tid*4; idx < 4096; idx += 1024){
    int r = idx >> 6, c = idx & 63;
    int row = rbase + r;
    float4 a = make_float4(0.f,0.f,0.f,0.f);
    if (row < P){
      ushort4 u = *(const ushort4*)&h1bf[(size_t)row*64 + c];
      float4 sc4 = *(const float4*)&scsh1[c];
      float4 sh4 = *(const float4*)&scsh1[64 + c];
      a.x = fmaf(sc4.x, bf2f(u.x), sh4.x); a.x = a.x > 0.f ? a.x : 0.f;
      a.y = fmaf(sc4.y, bf2f(u.y), sh4.y); a.y = a.y > 0.f ? a.y : 0.f;
      a.z = fmaf(sc4.z, bf2f(u.z), sh4.z); a.z = a.z > 0.f ? a.z : 0.f;
      a.w = fmaf(sc4.w, bf2f(u.w), sh4.w); a.w = a.w > 0.f ? a.w : 0.f;
    }
    *(float4*)&sZ[r][c] = a;
  }
  __syncthreads();
  float a2[4][2];
#pragma unroll
  for (int i=0;i<4;i++){ a2[i][0]=0.f; a2[i][1]=0.f; }
#pragma unroll 2
  for (int kb=0; kb<16; kb++){
    float4 zf[4];
    float2 wf[4];
#pragma unroll
    for (int i=0;i<4;i++) zf[i] = *(const float4*)&sZ[lr*4+i][kb*4];
#pragma unroll
    for (int kk=0;kk<4;kk++) wf[kk] = *(const float2*)&sW2[kb*4+kk][lc*2];
#pragma unroll
    for (int i=0;i<4;i++){
      a2[i][0] = fmaf(zf[i].x, wf[0].x, a2[i][0]);
      a2[i][1] = fmaf(zf[i].x, wf[0].y, a2[i][1]);
      a2[i][0] = fmaf(zf[i].y, wf[1].x, a2[i][0]);
      a2[i][1] = fmaf(zf[i].y, wf[1].y, a2[i][1]);
      a2[i][0] = fmaf(zf[i].z, wf[2].x, a2[i][0]);
      a2[i][1] = fmaf(zf[i].z, wf[2].y, a2[i][1]);
      a2[i][0] = fmaf(zf[i].w, wf[3].x, a2[i][0]);
      a2[i][1] = fmaf(zf[i].w, wf[3].y, a2[i][1]);
    }
  }
  float psum0=0.f, psum1=0.f, psq0=0.f, psq1=0.f;
#pragma unroll
  for (int i=0;i<4;i++){
    int row = rbase + lr*4 + i;
    if (row < P){
      float v0 = a2[i][0] + b2a;
      float v1 = a2[i][1] + b2b;
      *(float2*)&s2out[(size_t)row*32 + lc*2] = make_float2(v0, v1);
      psum0 += v0; psum1 += v1;
      psq0 += v0*v0; psq1 += v1*v1;
    }
  }
  __syncthreads();
  sred[lr][lc*2] = psum0; sred[lr][lc*2+1] = psum1;
  __syncthreads();
  if (tid < 32){
    float s = 0.f;
#pragma unroll
    for (int j=0;j<16;j++) s += sred[j][tid];
    atomicAdd(&gsum2[tid], s);
  }
  __syncthreads();
  sred[lr][lc*2] = psq0; sred[lr][lc*2+1] = psq1;
  __syncthreads();
  if (tid < 32){
    float s = 0.f;
#pragma unroll
    for (int j=0;j<16;j++) s += sred[j][tid];
    atomicAdd(&gsq2[tid], s);
  }
}

// ---------------- BN finalize ----------------
__global__ void bn_fin4_kernel(const float* __restrict__ stats,
    const float* __restrict__ g1, const float* __restrict__ be1, int l,
    float* __restrict__ scsh){
  int t = threadIdx.x;
  if (t >= 256) return;
  int gi = t>>6, c = t&63;
  float N = (gi==0) ? 1000.f : (gi==3) ? 20000.f : 200000.f;
  float invN = 1.f/N;
  float s = stats[gi*128 + c];
  float q = stats[gi*128 + 64 + c];
  float m = s*invN;
  float var = q*invN - m*m;
  float inv = rsqrtf(var + 1e-5f);
  float gg = g1[((size_t)l*4+gi)*64 + c];
  float bb = be1[((size_t)l*4+gi)*64 + c];
  float sc = gg*inv;
  scsh[gi*128 + c]      = sc;
  scsh[gi*128 + 64 + c] = bb - m*sc;
}

__global__ void bn_fin_kernel(const float* __restrict__ ssum, const float* __restrict__ ssq,
    const float* __restrict__ g, const float* __restrict__ be, float invN, int C,
    float* __restrict__ scsh){
  int c = threadIdx.x;
  if (c >= C) return;
  float m = ssum[c]*invN;
  float var = ssq[c]*invN - m*m;
  float inv = rsqrtf(var + 1e-5f);
  float s = g[c]*inv;
  scsh[c] = s; scsh[64+c] = be[c] - m*s;
}

// ---------------- final pass 3 ----------------
__global__ __launch_bounds__(256) void final_pass3_kernel(
    const float* __restrict__ s2, const float* __restrict__ Ws3, const float* __restrict__ bs3,
    const float* __restrict__ scsh2,
    float* __restrict__ outp, int P){
  __shared__ float w3[32], c2[32], h2[32];
  __shared__ float b3;
  if (threadIdx.x < 32){
    w3[threadIdx.x]=Ws3[threadIdx.x];
    c2[threadIdx.x]=scsh2[threadIdx.x];
    h2[threadIdx.x]=scsh2[64+threadIdx.x];
  }
  if (threadIdx.x == 0) b3 = bs3[0];
  __syncthreads();
  int r = blockIdx.x*blockDim.x + threadIdx.x;
  if (r >= P) return;
  float acc = b3;
  const float4* S4 = (const float4*)(s2 + (size_t)r*32);
#pragma unroll
  for (int k4=0;k4<8;k4++){
    float4 v = S4[k4];
    float a;
    a = c2[4*k4+0]*v.x + h2[4*k4+0]; acc += (a>0.f?a:0.f)*w3[4*k4+0];
    a = c2[4*k4+1]*v.y + h2[4*k4+1]; acc += (a>0.f?a:0.f)*w3[4*k4+1];
    a = c2[4*k4+2]*v.z + h2[4*k4+2]; acc += (a>0.f?a:0.f)*w3[4*k4+2];
    a = c2[4*k4+3]*v.w + h2[4*k4+3]; acc += (a>0.f?a:0.f)*w3[4*k4+3];
  }
  outp[r] = acc;
}

// ---------------- host ----------------
extern "C" void kernel_launch(void* const* d_in, const int* in_sizes, int n_in,
                              void* d_out, int out_size, void* d_ws, size_t ws_size,
                              hipStream_t stream){
  (void)in_sizes; (void)n_in; (void)out_size; (void)ws_size;
  const float* x_op   = (const float*)d_in[0];
  const float* x_ma   = (const float*)d_in[1];
  const float* x_jb   = (const float*)d_in[2];
  const float* Wenc_op= (const float*)d_in[3];
  const float* Wenc_ma= (const float*)d_in[4];
  const float* Wenc_jb= (const float*)d_in[5];
  const float* gW1_l0 = (const float*)d_in[6];
  const float* gW1_l12= (const float*)d_in[7];
  const float* gb1    = (const float*)d_in[8];
  const float* gg1    = (const float*)d_in[9];
  const float* gbe1   = (const float*)d_in[10];
  const float* gW2    = (const float*)d_in[11];
  const float* gb2    = (const float*)d_in[12];
  const float* geps   = (const float*)d_in[13];
  const float* Ws1    = (const float*)d_in[14];
  const float* bs1    = (const float*)d_in[15];
  const float* gs1    = (const float*)d_in[16];
  const float* bes1   = (const float*)d_in[17];
  const float* Ws2    = (const float*)d_in[18];
  const float* bs2    = (const float*)d_in[19];
  const float* gs2    = (const float*)d_in[20];
  const float* bes2   = (const float*)d_in[21];
  const float* Ws3    = (const float*)d_in[22];
  const float* bs3    = (const float*)d_in[23];
  const int* eom_s = (const int*)d_in[24];
  const int* eom_d = (const int*)d_in[25];
  const int* emo_s = (const int*)d_in[26];
  const int* emo_d = (const int*)d_in[27];
  const int* ejo_s = (const int*)d_in[28];
  const int* ejo_d = (const int*)d_in[29];
  const int* eoj_s = (const int*)d_in[30];
  const int* eoj_d = (const int*)d_in[31];
  const int* vpo = (const int*)d_in[32];
  const int* vpm = (const int*)d_in[33];
  const int* vpj = (const int*)d_in[34];
  float* outp = (float*)d_out;

  char* wsp = (char*)d_ws;
  auto alloc = [&](size_t bytes)->void*{
    void* p = (void*)wsp;
    wsp += (bytes + 255) & ~(size_t)255;
    return p;
  };
  float* P0 = (float*)alloc((size_t)N_OP_*64*4);
  float* P1 = (float*)alloc((size_t)N_OP_*64*4);
  float* P2 = (float*)alloc((size_t)N_OP_*64*4);
  float* J0 = (float*)alloc((size_t)N_JOB_*64*4);
  float* J1 = (float*)alloc((size_t)N_JOB_*64*4);
  float* M0 = (float*)alloc((size_t)N_MACH_*64*4);
  float* M1 = (float*)alloc((size_t)N_MACH_*64*4);
  float* S2 = (float*)alloc((size_t)N_PAIRS_*32*4);   // doubles as bf16 h1
  int* off_all  = (int*)alloc((size_t)(TOTC_+1)*4);
  int* cnt_all  = (int*)alloc((size_t)TOTC_*4);
  int* elist_all= (int*)alloc((size_t)E_TOT_*4);
  int* partials = (int*)alloc(1024*4);
  float* lstats = (float*)alloc(512*4);
  float* lscsh  = (float*)alloc(512*4);
  float* fstats = (float*)alloc(512*4);

  // -------- encode --------
  encode_kernel<8><<<CDIV(N_OP_,256),256,0,stream>>>(x_op, Wenc_op, P0, N_OP_);
  encode_kernel<4><<<CDIV(N_MACH_,256),256,0,stream>>>(x_ma, Wenc_ma, M0, N_MACH_);
  encode_kernel<4><<<CDIV(N_JOB_,256),256,0,stream>>>(x_jb, Wenc_jb, J0, N_JOB_);

  // -------- merged CSR build (om sub-bucketed 64x) --------
  hipMemsetAsync(cnt_all, 0, (size_t)TOTC_*4, stream);
  const int GE = CDIV(E_TOT_/8, 256);
  hist_all_kernel<<<GE,256,0,stream>>>(eom_d, emo_d, ejo_d, eoj_d, cnt_all);
  const int NB = CDIV(TOTC_, 2048);   // 237
  scan_block_sums<<<NB,256,0,stream>>>(cnt_all, TOTC_, partials);
  scan_partials<<<1,256,0,stream>>>(partials, NB, off_all + TOTC_);
  scan_write_offsets<<<NB,256,0,stream>>>(cnt_all, TOTC_, partials, off_all);
  hipMemcpyAsync(cnt_all, off_all, (size_t)TOTC_*4, hipMemcpyDeviceToDevice, stream);
  fill_all_kernel<<<GE,256,0,stream>>>(eom_s, eom_d, emo_s, emo_d,
                                       ejo_s, ejo_d, eoj_s, eoj_d,
                                       cnt_all, elist_all);

  float *Xop=P0, *Aop=P1, *Bop=P2;
  float *Xjb=J0, *Ajb=J1;
  float *Xma=M0, *Ama=M1;

  const int TA = CDIV(N_MACH_,64) + 2*CDIV(N_OP_,64) + CDIV(N_JOB_,64);  // 6579
  const int TB = CDIV(N_MACH_,64) + CDIV(N_OP_,64) + CDIV(N_JOB_,64);    // 3454

  for (int l=0; l<3; l++){
    int Din = (l==0) ? 32 : 64;
    hipMemsetAsync(lstats, 0, 512*4, stream);
    const float *W1m, *W1a, *W1b, *W1j;
    if (l==0){
      W1m = gW1_l0 + (size_t)0*32*64; W1a = gW1_l0 + (size_t)1*32*64;
      W1b = gW1_l0 + (size_t)2*32*64; W1j = gW1_l0 + (size_t)3*32*64;
    } else {
      W1m = gW1_l12 + ((size_t)(l-1)*4+0)*64*64; W1a = gW1_l12 + ((size_t)(l-1)*4+1)*64*64;
      W1b = gW1_l12 + ((size_t)(l-1)*4+2)*64*64; W1j = gW1_l12 + ((size_t)(l-1)*4+3)*64*64;
    }
    const float* b1m = gb1 + ((size_t)l*4+0)*64; const float* b1a = gb1 + ((size_t)l*4+1)*64;
    const float* b1b = gb1 + ((size_t)l*4+2)*64; const float* b1j = gb1 + ((size_t)l*4+3)*64;
    // machine aggregation (64 sub-buckets per machine; block per machine)
    agg_block_kernel<<<N_MACH_,256,0,stream>>>(off_all + B_OM_, elist_all, Xop, Ama, N_MACH_, Din);
    // fused gather(op/job) + partA MFMA hi/lo GEMM (4 GINs, one dispatch; machines read pre-agg)
    if (l==0){
      partA_fused_kernel<32><<<TA,256,0,stream>>>(
        off_all, elist_all, Xop, Xma, Xjb,
        Ama, Aop, Bop, Ajb,
        W1m, W1a, W1b, W1j, b1m, b1a, b1b, b1j,
        lstats, geps, 0);
    } else {
      partA_fused_kernel<64><<<TA,256,0,stream>>>(
        off_all, elist_all, Xop, Xma, Xjb,
        Ama, Aop, Bop, Ajb,
        W1m, W1a, W1b, W1j, b1m, b1a, b1b, b1j,
        lstats, geps, l*4);
    }
    bn_fin4_kernel<<<1,256,0,stream>>>(lstats, gg1, gbe1, l, lscsh);
    const float* W2m = gW2 + ((size_t)l*4+0)*64*64; const float* b2m = gb2 + ((size_t)l*4+0)*64;
    const float* W2a = gW2 + ((size_t)l*4+1)*64*64; const float* b2a = gb2 + ((size_t)l*4+1)*64;
    const float* W2b = gW2 + ((size_t)l*4+2)*64*64; const float* b2b = gb2 + ((size_t)l*4+2)*64;
    const float* W2j = gW2 + ((size_t)l*4+3)*64*64; const float* b2j = gb2 + ((size_t)l*4+3)*64;
    if (l==0){
      partB_batch_kernel<false><<<TB,256,0,stream>>>(
        Ama, Xma, W2m, b2m, lscsh+0,   N_MACH_,
        Aop, Bop, Xop, W2a, W2b, b2a, b2b, lscsh+128, lscsh+256, N_OP_,
        Ajb, Xjb, W2j, b2j, lscsh+384, N_JOB_);
    } else {
      partB_batch_kernel<true><<<TB,256,0,stream>>>(
        Ama, Xma, W2m, b2m, lscsh+0,   N_MACH_,
        Aop, Bop, Xop, W2a, W2b, b2a, b2b, lscsh+128, lscsh+256, N_OP_,
        Ajb, Xjb, W2j, b2j, lscsh+384, N_JOB_);
    }
    { float* t=Xma; Xma=Ama; Ama=t; }
    { float* t=Xop; Xop=Aop; Aop=t; }
    { float* t=Xjb; Xjb=Ajb; Ajb=t; }
  }

  // -------- final MLP over 500k gathered pairs --------
  float* fsum1 = fstats;       float* fsq1 = fstats+64;
  float* fsum2 = fstats+128;   float* fsq2 = fstats+192;
  float* scsh1 = fstats+256;
  float* scsh2 = fstats+384;
  unsigned short* H1BF = (unsigned short*)S2;
  hipMemsetAsync(fstats, 0, 256*4, stream);
  fp1_gemm_kernel<<<2048,256,0,stream>>>(Xop,Xma,Xjb,vpo,vpm,vpj,Ws1,bs1,H1BF,N_PAIRS_,fsum1,fsq1);
  bn_fin_kernel<<<1,64,0,stream>>>(fsum1,fsq1,gs1,bes1, 1.f/(float)N_PAIRS_, 64, scsh1);
  fp2_lite_kernel<<<CDIV(N_PAIRS_,64),256,0,stream>>>(scsh1, Ws2, bs2, H1BF, S2, N_PAIRS_, fsum2, fsq2);
  bn_fin_kernel<<<1,32,0,stream>>>(fsum2,fsq2,gs2,bes2, 1.f/(float)N_PAIRS_, 32, scsh2);
  final_pass3_kernel<<<CDIV(N_PAIRS_,256),256,0,stream>>>(S2, Ws3, bs3, scsh2, outp, N_PAIRS_);
}

// Round 17
// 1317.916 us; speedup vs baseline: 1.0544x; 1.0544x over previous
//
#include <hip/hip_runtime.h>
#include <math.h>

#define N_OP_   200000
#define N_MACH_ 1000
#define N_JOB_  20000
#define E_OM_   1000000
#define E_JO_   200000
#define N_PAIRS_ 500000

// merged CSR layout; om machines split into 64 sub-buckets each (atomic decontention)
#define B_OM_ 0
#define B_MO_ 64000
#define B_JO_ 264000
#define B_OJ_ 464000
#define TOTC_ 484000
#define E_TOT_ 2400000

// merged enc+hist dispatch partition
#define GH_   1172   // CDIV(E_TOT_/8, 256)
#define G_OP_ 782    // CDIV(N_OP_, 256)
#define G_MA_ 4      // CDIV(N_MACH_, 256)
#define G_JB_ 79     // CDIV(N_JOB_, 256)

#define CDIV(a,b) (((a)+(b)-1)/(b))

typedef __attribute__((ext_vector_type(8))) short short8v;   // 8 x bf16
typedef __attribute__((ext_vector_type(4))) float f32x4;

__device__ __forceinline__ unsigned short f2bf(float f){
  unsigned int u = __float_as_uint(f);
  return (unsigned short)((u + 0x7fffu + ((u>>16)&1u)) >> 16);
}
__device__ __forceinline__ float bf2f(unsigned short h){
  return __uint_as_float(((unsigned int)h)<<16);
}

// ---------------- encode body (device, compile-time DIN) ----------------
template<int DIN>
__device__ __forceinline__ void encode_body(const float* __restrict__ x,
    const float* __restrict__ W, float* __restrict__ out, int N, float* sW, int bid){
  if (threadIdx.x < DIN*16) sW[threadIdx.x] = W[threadIdx.x];
  __syncthreads();
  int i = bid*256 + threadIdx.x;
  if (i >= N) return;
  float xv[DIN];
#pragma unroll
  for (int k=0;k<DIN;k++) xv[k] = x[i*DIN+k];
#pragma unroll
  for (int j=0;j<16;j++){
    float h = 0.f;
#pragma unroll
    for (int k=0;k<DIN;k++) h = fmaf(xv[k], sW[k*16+j], h);
    float s, c;
    sincosf(h, &s, &c);
    out[(size_t)i*64 + j]      = s;
    out[(size_t)i*64 + 16 + j] = c;
  }
}

// ---------------- merged CSR helpers (om -> 64 sub-buckets/machine) ----------------
__device__ __forceinline__ int edge_cidx(int e,
    const int* __restrict__ eom_d, const int* __restrict__ emo_d,
    const int* __restrict__ ejo_d, const int* __restrict__ eoj_d){
  if (e < E_OM_)            return B_OM_ + eom_d[e]*64 + (e & 63);
  else if (e < 2*E_OM_)     return B_MO_ + emo_d[e - E_OM_];
  else if (e < 2*E_OM_+E_JO_) return B_JO_ + ejo_d[e - 2*E_OM_];
  else                      return B_OJ_ + eoj_d[e - 2*E_OM_ - E_JO_];
}
__device__ __forceinline__ int edge_src(int e,
    const int* __restrict__ eom_s, const int* __restrict__ emo_s,
    const int* __restrict__ ejo_s, const int* __restrict__ eoj_s){
  if (e < E_OM_)            return eom_s[e];
  else if (e < 2*E_OM_)     return emo_s[e - E_OM_];
  else if (e < 2*E_OM_+E_JO_) return ejo_s[e - 2*E_OM_];
  else                      return eoj_s[e - 2*E_OM_ - E_JO_];
}

// ---------------- merged encode + histogram (one dispatch; co-resident overlap) ----------------
__global__ __launch_bounds__(256) void enc_hist_kernel(
    const float* __restrict__ xop, const float* __restrict__ Wop, float* __restrict__ Pop,
    const float* __restrict__ xma, const float* __restrict__ Wma, float* __restrict__ Pma,
    const float* __restrict__ xjb, const float* __restrict__ Wjb, float* __restrict__ Pjb,
    const int* __restrict__ eom_d, const int* __restrict__ emo_d,
    const int* __restrict__ ejo_d, const int* __restrict__ eoj_d,
    int* __restrict__ cnt)
{
  __shared__ float sW[128];
  int b = blockIdx.x;
  if (b < GH_){
    const int gsz = GH_*256;
    int i0 = b*256 + threadIdx.x;
    for (int base = i0; base < E_TOT_; base += 8*gsz){
      int c[8]; bool act[8];
#pragma unroll
      for (int j=0;j<8;j++){
        int e = base + j*gsz;
        act[j] = (e < E_TOT_);
        if (act[j]) c[j] = edge_cidx(e, eom_d, emo_d, ejo_d, eoj_d);
      }
#pragma unroll
      for (int j=0;j<8;j++) if (act[j]) atomicAdd(&cnt[c[j]], 1);
    }
  } else if (b < GH_ + G_OP_){
    encode_body<8>(xop, Wop, Pop, N_OP_, sW, b - GH_);
  } else if (b < GH_ + G_OP_ + G_MA_){
    encode_body<4>(xma, Wma, Pma, N_MACH_, sW, b - GH_ - G_OP_);
  } else {
    encode_body<4>(xjb, Wjb, Pjb, N_JOB_, sW, b - GH_ - G_OP_ - G_MA_);
  }
}

__global__ __launch_bounds__(256) void fill_all_kernel(
    const int* __restrict__ eom_s, const int* __restrict__ eom_d,
    const int* __restrict__ emo_s, const int* __restrict__ emo_d,
    const int* __restrict__ ejo_s, const int* __restrict__ ejo_d,
    const int* __restrict__ eoj_s, const int* __restrict__ eoj_d,
    int* __restrict__ cursor, int* __restrict__ elist){
  int gsz = gridDim.x*blockDim.x;
  int i0 = blockIdx.x*blockDim.x + threadIdx.x;
  for (int base = i0; base < E_TOT_; base += 8*gsz){
    int cidx[8], src[8]; bool act[8];
#pragma unroll
    for (int j=0;j<8;j++){
      int e = base + j*gsz;
      act[j] = (e < E_TOT_);
      if (act[j]){
        cidx[j] = edge_cidx(e, eom_d, emo_d, ejo_d, eoj_d);
        src[j]  = edge_src (e, eom_s, emo_s, ejo_s, eoj_s);
      }
    }
    int p[8];
#pragma unroll
    for (int j=0;j<8;j++) if (act[j]) p[j] = atomicAdd(&cursor[cidx[j]], 1);
#pragma unroll
    for (int j=0;j<8;j++) if (act[j]) elist[p[j]] = src[j];
  }
}

// scan over 2048 elements per block (TOTC_=484000 -> NB=237 <= 256)
__global__ void scan_block_sums(const int* __restrict__ cnt, int N, int* __restrict__ partials){
  __shared__ int red[256];
  int base = blockIdx.x*2048;
  int s = 0;
#pragma unroll
  for (int j=0;j<8;j++){ int i = base + threadIdx.x + j*256; if (i<N) s += cnt[i]; }
  red[threadIdx.x] = s; __syncthreads();
  for (int st=128; st>0; st>>=1){ if (threadIdx.x<st) red[threadIdx.x]+=red[threadIdx.x+st]; __syncthreads(); }
  if (threadIdx.x==0) partials[blockIdx.x] = red[0];
}

__global__ void scan_partials(int* __restrict__ partials, int NB, int* __restrict__ offN){
  __shared__ int buf[256];
  int v = (threadIdx.x < NB) ? partials[threadIdx.x] : 0;
  buf[threadIdx.x] = v; __syncthreads();
  int acc = v;
  for (int st=1; st<256; st<<=1){
    int t = (threadIdx.x >= st) ? buf[threadIdx.x-st] : 0;
    __syncthreads();
    acc += t; buf[threadIdx.x] = acc;
    __syncthreads();
  }
  if (threadIdx.x < NB) partials[threadIdx.x] = acc - v;  // exclusive
  if (threadIdx.x == NB-1) offN[0] = acc;                 // total
}

__global__ void scan_write_offsets(const int* __restrict__ cnt, int N,
    const int* __restrict__ partials, int* __restrict__ off){
  __shared__ int buf[256];
  int base = blockIdx.x*2048;
  int v[8]; int s = 0;
#pragma unroll
  for (int j=0;j<8;j++){ int i = base + threadIdx.x*8 + j; v[j] = (i<N)?cnt[i]:0; s += v[j]; }
  buf[threadIdx.x] = s; __syncthreads();
  int acc = s;
  for (int st=1; st<256; st<<=1){
    int t = (threadIdx.x >= st) ? buf[threadIdx.x-st] : 0;
    __syncthreads();
    acc += t; buf[threadIdx.x] = acc;
    __syncthreads();
  }
  int ex = partials[blockIdx.x] + acc - s;
#pragma unroll
  for (int j=0;j<8;j++){ int i = base + threadIdx.x*8 + j; if (i<N) off[i] = ex; ex += v[j]; }
}

// ---------------- machine aggregation (64 sub-buckets per machine; block per machine) ----------------
__global__ __launch_bounds__(256) void agg_block_kernel(const int* __restrict__ off,
    const int* __restrict__ srcs, const float* __restrict__ feat,
    float* __restrict__ outp, int Ndst, int D){
  __shared__ float red[4][64];
  int m = blockIdx.x;
  if (m >= Ndst) return;
  int g = threadIdx.x >> 6, lane = threadIdx.x & 63;
  int s = off[m*64], e = off[m*64 + 64];
  float acc = 0.f;
  for (int base = s + g*64; base < e; base += 256){
    int cnt = e - base; if (cnt > 64) cnt = 64;
    int r = (lane < cnt) ? srcs[base + lane] : 0;
    int i = 0;
    for (; i + 4 <= cnt; i += 4){
      int r0 = __shfl(r, i), r1 = __shfl(r, i+1), r2 = __shfl(r, i+2), r3 = __shfl(r, i+3);
      float v0 = feat[(size_t)r0*64 + lane];
      float v1 = feat[(size_t)r1*64 + lane];
      float v2 = feat[(size_t)r2*64 + lane];
      float v3 = feat[(size_t)r3*64 + lane];
      acc += (v0 + v1) + (v2 + v3);
    }
    for (; i < cnt; i++){
      int ri = __shfl(r, i);
      acc += feat[(size_t)ri*64 + lane];
    }
  }
  red[g][lane] = acc;
  __syncthreads();
  if (g==0 && lane<D)
    outp[(size_t)m*64+lane] = red[0][lane]+red[1][lane]+red[2][lane]+red[3][lane];
}

// ---------------- fused partA (fp32): seg0 reads pre-agg; seg1-3 CSR-gather; + GEMM + stats ----------------
template<int K>
__global__ __launch_bounds__(256,3) void partA_fused_kernel(
    const int* __restrict__ off_all, const int* __restrict__ elist,
    const float* __restrict__ Xop, const float* __restrict__ Xma, const float* __restrict__ Xjb,
    float* hm, float* ho1, float* ho2, float* hj,
    const float* __restrict__ Wm, const float* __restrict__ Wa,
    const float* __restrict__ Wb, const float* __restrict__ Wj,
    const float* __restrict__ bm, const float* __restrict__ ba,
    const float* __restrict__ bb, const float* __restrict__ bj,
    float* __restrict__ lstats,
    const float* __restrict__ epsp, int ebase)
{
  constexpr int KP = K + 4;
  constexpr int NF4 = K/16;
  __shared__ float sW[K][64];
  __shared__ float sZ[64][KP];
  __shared__ float sred[16][64];
  const int tid = threadIdx.x;
  const int lc = tid & 15, lr = tid >> 4;
  const int Tm = (N_MACH_+63)>>6, To = (N_OP_+63)>>6;
  int t = blockIdx.x;
  int seg, tile;
  if (t < Tm){ seg=0; tile=t; }
  else if (t < Tm+To){ seg=1; tile=t-Tm; }
  else if (t < Tm+2*To){ seg=2; tile=t-Tm-To; }
  else { seg=3; tile=t-Tm-2*To; }
  float* z            = seg==0?hm:seg==1?ho1:seg==2?ho2:hj;
  const float* x      = seg==0?Xma:seg==3?Xjb:Xop;
  const float* feat   = seg==0?Xop:seg==1?Xma:seg==2?Xjb:Xop;
  const float* W      = seg==0?Wm:seg==1?Wa:seg==2?Wb:Wj;
  const float* b      = seg==0?bm:seg==1?ba:seg==2?bb:bj;
  const int N         = seg==0?N_MACH_:seg==3?N_JOB_:N_OP_;
  const int* offs     = off_all + (seg==0?B_OM_:seg==1?B_MO_:seg==2?B_JO_:B_OJ_);
  float* st           = lstats + seg*128;
  const float e1 = 1.0f + epsp[ebase + seg];
  for (int idx = tid*4; idx < K*64; idx += 1024){
    int k = idx >> 6, c = idx & 63;
    *(float4*)&sW[k][c] = *(const float4*)&W[(size_t)k*64 + c];
  }
  float4 bias4 = *(const float4*)&b[lc*4];
  const int rbase = tile << 6;
  {
    const int r = tid >> 2, q = tid & 3;
    const int cbase = q*(K/4);
    int row = rbase + r;
    float4 a4[NF4];
#pragma unroll
    for (int f=0; f<NF4; f++) a4[f] = make_float4(0.f,0.f,0.f,0.f);
    if (row < N){
      if (seg == 0){
        const float4* H4 = (const float4*)&z[(size_t)row*64 + cbase];
#pragma unroll
        for (int f=0; f<NF4; f++) a4[f] = H4[f];
      } else {
        int s = offs[row], e = offs[row+1];
        int i = s;
        for (; i+2<=e; i+=2){
          int s0 = elist[i], s1 = elist[i+1];
          const float4* F0 = (const float4*)&feat[(size_t)s0*64 + cbase];
          const float4* F1 = (const float4*)&feat[(size_t)s1*64 + cbase];
          float4 v0[NF4], v1[NF4];
#pragma unroll
          for (int f=0; f<NF4; f++){ v0[f]=F0[f]; v1[f]=F1[f]; }
#pragma unroll
          for (int f=0; f<NF4; f++){
            a4[f].x += v0[f].x + v1[f].x;
            a4[f].y += v0[f].y + v1[f].y;
            a4[f].z += v0[f].z + v1[f].z;
            a4[f].w += v0[f].w + v1[f].w;
          }
        }
        if (i < e){
          int s0 = elist[i];
          const float4* F0 = (const float4*)&feat[(size_t)s0*64 + cbase];
#pragma unroll
          for (int f=0; f<NF4; f++){
            float4 v = F0[f];
            a4[f].x += v.x; a4[f].y += v.y; a4[f].z += v.z; a4[f].w += v.w;
          }
        }
      }
      const float4* X4 = (const float4*)&x[(size_t)row*64 + cbase];
#pragma unroll
      for (int f=0; f<NF4; f++){
        float4 xv = X4[f];
        a4[f].x = fmaf(e1, xv.x, a4[f].x);
        a4[f].y = fmaf(e1, xv.y, a4[f].y);
        a4[f].z = fmaf(e1, xv.z, a4[f].z);
        a4[f].w = fmaf(e1, xv.w, a4[f].w);
      }
    }
#pragma unroll
    for (int f=0; f<NF4; f++) *(float4*)&sZ[r][cbase + f*4] = a4[f];
  }
  __syncthreads();
  float acc[4][4];
#pragma unroll
  for (int i=0;i<4;i++){ acc[i][0]=0.f; acc[i][1]=0.f; acc[i][2]=0.f; acc[i][3]=0.f; }
#pragma unroll 2
  for (int kb = 0; kb < K/4; kb++){
    float4 zf[4], wf[4];
#pragma unroll
    for (int i=0;i<4;i++) zf[i] = *(const float4*)&sZ[lr*4+i][kb*4];
#pragma unroll
    for (int kk=0;kk<4;kk++) wf[kk] = *(const float4*)&sW[kb*4+kk][lc*4];
#pragma unroll
    for (int i=0;i<4;i++){
      acc[i][0] = fmaf(zf[i].x, wf[0].x, acc[i][0]);
      acc[i][1] = fmaf(zf[i].x, wf[0].y, acc[i][1]);
      acc[i][2] = fmaf(zf[i].x, wf[0].z, acc[i][2]);
      acc[i][3] = fmaf(zf[i].x, wf[0].w, acc[i][3]);
      acc[i][0] = fmaf(zf[i].y, wf[1].x, acc[i][0]);
      acc[i][1] = fmaf(zf[i].y, wf[1].y, acc[i][1]);
      acc[i][2] = fmaf(zf[i].y, wf[1].z, acc[i][2]);
      acc[i][3] = fmaf(zf[i].y, wf[1].w, acc[i][3]);
      acc[i][0] = fmaf(zf[i].z, wf[2].x, acc[i][0]);
      acc[i][1] = fmaf(zf[i].z, wf[2].y, acc[i][1]);
      acc[i][2] = fmaf(zf[i].z, wf[2].z, acc[i][2]);
      acc[i][3] = fmaf(zf[i].z, wf[2].w, acc[i][3]);
      acc[i][0] = fmaf(zf[i].w, wf[3].x, acc[i][0]);
      acc[i][1] = fmaf(zf[i].w, wf[3].y, acc[i][1]);
      acc[i][2] = fmaf(zf[i].w, wf[3].z, acc[i][2]);
      acc[i][3] = fmaf(zf[i].w, wf[3].w, acc[i][3]);
    }
  }
  float4 psum = make_float4(0.f,0.f,0.f,0.f), psq = make_float4(0.f,0.f,0.f,0.f);
#pragma unroll
  for (int i=0;i<4;i++){
    int row = rbase + lr*4 + i;
    if (row < N){
      float4 o;
      o.x = acc[i][0] + bias4.x;
      o.y = acc[i][1] + bias4.y;
      o.z = acc[i][2] + bias4.z;
      o.w = acc[i][3] + bias4.w;
      *(float4*)&z[(size_t)row*64 + lc*4] = o;
      psum.x += o.x; psum.y += o.y; psum.z += o.z; psum.w += o.w;
      psq.x += o.x*o.x; psq.y += o.y*o.y; psq.z += o.z*o.z; psq.w += o.w*o.w;
    }
  }
  __syncthreads();
  *(float4*)&sred[lr][lc*4] = psum;
  __syncthreads();
  if (tid < 64){
    float s = 0.f;
#pragma unroll
    for (int j=0;j<16;j++) s += sred[j][tid];
    atomicAdd(&st[tid], s);
  }
  __syncthreads();
  *(float4*)&sred[lr][lc*4] = psq;
  __syncthreads();
  if (tid < 64){
    float s = 0.f;
#pragma unroll
    for (int j=0;j<16;j++) s += sred[j][tid];
    atomicAdd(&st[64+tid], s);
  }
}

// ---------------- batched partB (MFMA bf16): 3 segments (mach, op-dual, job) ----------------
template<bool RESID>
__global__ __launch_bounds__(256,3) void partB_batch_kernel(
    float* h0, const float* x0, const float* W20, const float* b20, const float* sc0, int N0,
    float* hA, const float* hBp, const float* x1, const float* W2a, const float* W2b,
    const float* b2a_, const float* b2b_, const float* scA, const float* scB, int N1,
    float* h3, const float* x3, const float* W23, const float* b23, const float* sc3, int N3)
{
  __shared__ unsigned short sA[64][72];   // bf16 activations, padded
  __shared__ unsigned short sB[64][72];   // bf16 W^T: sB[col][k]
  const int tid = threadIdx.x;
  const int lane = tid & 63, w = tid >> 6;
  const int lo = lane & 15, hi = lane >> 4;
  const int T0=(N0+63)>>6, T1=(N1+63)>>6;
  int t = blockIdx.x;
  int seg, tile;
  if (t < T0){ seg=0; tile=t; }
  else if (t < T0+T1){ seg=1; tile=t-T0; }
  else { seg=2; tile=t-T0-T1; }
  const int N = seg==0?N0:seg==1?N1:N3;
  float* hout = seg==0?h0:seg==1?hA:h3;
  const float* x = seg==0?x0:seg==1?x1:x3;
  const int rbase = tile << 6;
  const int nsrc = (seg==1) ? 2 : 1;
  f32x4 acc[4];
#pragma unroll
  for (int n=0;n<4;n++) acc[n] = (f32x4){0.f,0.f,0.f,0.f};
  for (int s=0; s<nsrc; s++){
    const float* hsrc = (seg==1) ? (s==0? (const float*)hA : hBp)
                                 : (seg==0? (const float*)h0 : (const float*)h3);
    const float* Wp   = (seg==1) ? (s==0? W2a : W2b) : (seg==0? W20 : W23);
    const float* scp  = (seg==1) ? (s==0? scA : scB) : (seg==0? sc0 : sc3);
    __syncthreads();
    // stage W^T (bf16): sB[c][k]
    for (int idx = tid; idx < 1024; idx += 256){
      int k = idx >> 4, c4 = (idx & 15)*4;
      float4 wv = *(const float4*)&Wp[(size_t)k*64 + c4];
      sB[c4+0][k] = f2bf(wv.x);
      sB[c4+1][k] = f2bf(wv.y);
      sB[c4+2][k] = f2bf(wv.z);
      sB[c4+3][k] = f2bf(wv.w);
    }
    // stage A = relu(BN(h)) (bf16)
    for (int idx = tid; idx < 1024; idx += 256){
      int r = idx >> 4, c4 = (idx & 15)*4;
      int row = rbase + r;
      ushort4 zz = make_ushort4(0,0,0,0);
      if (row < N){
        float4 hv = *(const float4*)&hsrc[(size_t)row*64 + c4];
        float4 sc4 = *(const float4*)&scp[c4];
        float4 sh4 = *(const float4*)&scp[64 + c4];
        float a0 = fmaf(sc4.x, hv.x, sh4.x); a0 = a0>0.f?a0:0.f;
        float a1 = fmaf(sc4.y, hv.y, sh4.y); a1 = a1>0.f?a1:0.f;
        float a2 = fmaf(sc4.z, hv.z, sh4.z); a2 = a2>0.f?a2:0.f;
        float a3 = fmaf(sc4.w, hv.w, sh4.w); a3 = a3>0.f?a3:0.f;
        zz = make_ushort4(f2bf(a0), f2bf(a1), f2bf(a2), f2bf(a3));
      }
      *(ushort4*)&sA[r][c4] = zz;
    }
    __syncthreads();
    short8v af0 = *(const short8v*)&sA[w*16 + lo][hi*8];
    short8v af1 = *(const short8v*)&sA[w*16 + lo][32 + hi*8];
#pragma unroll
    for (int n=0;n<4;n++){
      short8v bf0 = *(const short8v*)&sB[n*16 + lo][hi*8];
      short8v bf1 = *(const short8v*)&sB[n*16 + lo][32 + hi*8];
      acc[n] = __builtin_amdgcn_mfma_f32_16x16x32_bf16(af0, bf0, acc[n], 0, 0, 0);
      acc[n] = __builtin_amdgcn_mfma_f32_16x16x32_bf16(af1, bf1, acc[n], 0, 0, 0);
    }
  }
  // epilogue: bias (+resid) + store. D mapping: col = lo (+16n), row = hi*4 + j.
#pragma unroll
  for (int n=0;n<4;n++){
    int col = n*16 + lo;
    float bv;
    if (seg==1) bv = b2a_[col] + b2b_[col];
    else if (seg==0) bv = b20[col];
    else bv = b23[col];
#pragma unroll
    for (int j=0;j<4;j++){
      int row = rbase + w*16 + hi*4 + j;
      if (row < N){
        float v = acc[n][j] + bv;
        if (RESID) v += x[(size_t)row*64 + col];
        hout[(size_t)row*64 + col] = v;
      }
    }
  }
}

// ---------------- fp1 (MFMA bf16): gather-GEMM (K=192) -> h1 bf16 + stats ----------------
__global__ __launch_bounds__(256,3) void fp1_gemm_kernel(
    const float* __restrict__ Xop, const float* __restrict__ Xma, const float* __restrict__ Xjb,
    const int* __restrict__ vpo, const int* __restrict__ vpm, const int* __restrict__ vpj,
    const float* __restrict__ Ws1, const float* __restrict__ bs1,
    unsigned short* __restrict__ h1bf,
    int P, float* __restrict__ gsum, float* __restrict__ gsq)
{
  __shared__ unsigned short sA[64][72];
  __shared__ unsigned short sB[64][72];
  __shared__ float sred[16][64];
  const int tid = threadIdx.x;
  const int lane = tid & 63, w = tid >> 6;
  const int lo = lane & 15, hi = lane >> 4;
  float ps[4] = {0.f,0.f,0.f,0.f};
  float pq[4] = {0.f,0.f,0.f,0.f};
  const int ntiles = (P + 63) >> 6;
  for (int t = blockIdx.x; t < ntiles; t += gridDim.x){
    const int rbase = t << 6;
    f32x4 acc[4];
#pragma unroll
    for (int n=0;n<4;n++) acc[n] = (f32x4){0.f,0.f,0.f,0.f};
    for (int s=0; s<3; s++){
      const int* vps = (s==0) ? vpo : (s==1) ? vpm : vpj;
      const float* Xs = (s==0) ? Xop : (s==1) ? Xma : Xjb;
      __syncthreads();
      // stage W chunk transposed (bf16)
      for (int idx = tid; idx < 1024; idx += 256){
        int k = idx >> 4, c4 = (idx & 15)*4;
        float4 wv = *(const float4*)&Ws1[(size_t)(s*64 + k)*64 + c4];
        sB[c4+0][k] = f2bf(wv.x);
        sB[c4+1][k] = f2bf(wv.y);
        sB[c4+2][k] = f2bf(wv.z);
        sB[c4+3][k] = f2bf(wv.w);
      }
      // stage gathered features (bf16)
      for (int idx = tid; idx < 1024; idx += 256){
        int r = idx >> 4, c4 = (idx & 15)*4;
        int row = rbase + r;
        ushort4 zz = make_ushort4(0,0,0,0);
        if (row < P){
          int nd = vps[row];
          float4 z = *(const float4*)&Xs[(size_t)nd*64 + c4];
          zz = make_ushort4(f2bf(z.x), f2bf(z.y), f2bf(z.z), f2bf(z.w));
        }
        *(ushort4*)&sA[r][c4] = zz;
      }
      __syncthreads();
      short8v af0 = *(const short8v*)&sA[w*16 + lo][hi*8];
      short8v af1 = *(const short8v*)&sA[w*16 + lo][32 + hi*8];
#pragma unroll
      for (int n=0;n<4;n++){
        short8v bf0 = *(const short8v*)&sB[n*16 + lo][hi*8];
        short8v bf1 = *(const short8v*)&sB[n*16 + lo][32 + hi*8];
        acc[n] = __builtin_amdgcn_mfma_f32_16x16x32_bf16(af0, bf0, acc[n], 0, 0, 0);
        acc[n] = __builtin_amdgcn_mfma_f32_16x16x32_bf16(af1, bf1, acc[n], 0, 0, 0);
      }
    }
    // epilogue: bias + store bf16 + stats
#pragma unroll
    for (int n=0;n<4;n++){
      int col = n*16 + lo;
      float bv = bs1[col];
#pragma unroll
      for (int j=0;j<4;j++){
        int row = rbase + w*16 + hi*4 + j;
        if (row < P){
          float v = acc[n][j] + bv;
          h1bf[(size_t)row*64 + col] = f2bf(v);
          ps[n] += v; pq[n] += v*v;
        }
      }
    }
  }
  // block reduction of per-lane column partials
  __syncthreads();
#pragma unroll
  for (int n=0;n<4;n++) sred[w*4 + hi][n*16 + lo] = ps[n];
  __syncthreads();
  if (tid < 64){
    float s = 0.f;
#pragma unroll
    for (int j=0;j<16;j++) s += sred[j][tid];
    atomicAdd(&gsum[tid], s);
  }
  __syncthreads();
#pragma unroll
  for (int n=0;n<4;n++) sred[w*4 + hi][n*16 + lo] = pq[n];
  __syncthreads();
  if (tid < 64){
    float s = 0.f;
#pragma unroll
    for (int j=0;j<16;j++) s += sred[j][tid];
    atomicAdd(&gsq[tid], s);
  }
}

// ---------------- fp2_lite: read bf16 h1, BN+ReLU, @Ws2+bs2 -> s2 (in place) + stats2 ----------------
__global__ __launch_bounds__(256,3) void fp2_lite_kernel(
    const float* __restrict__ scsh1,
    const float* __restrict__ Ws2, const float* __restrict__ bs2,
    const unsigned short* __restrict__ h1bf,
    float* __restrict__ s2out, int P,
    float* __restrict__ gsum2, float* __restrict__ gsq2)
{
  __shared__ float sZ[64][68];
  __shared__ float sW2[64][32];
  __shared__ float sred[16][64];
  const int tid = threadIdx.x;
  const int lc = tid & 15, lr = tid >> 4;
  for (int idx = tid*4; idx < 2048; idx += 1024){
    int k = idx >> 5, c = idx & 31;
    *(float4*)&sW2[k][c] = *(const float4*)&Ws2[(size_t)k*32 + c];
  }
  const float b2a = bs2[lc*2], b2b = bs2[lc*2+1];
  const int rbase = blockIdx.x << 6;
  for (int idx = tid*4; idx < 4096; idx += 1024){
    int r = idx >> 6, c = idx & 63;
    int row = rbase + r;
    float4 a = make_float4(0.f,0.f,0.f,0.f);
    if (row < P){
      ushort4 u = *(const ushort4*)&h1bf[(size_t)row*64 + c];
      float4 sc4 = *(const float4*)&scsh1[c];
      float4 sh4 = *(const float4*)&scsh1[64 + c];
      a.x = fmaf(sc4.x, bf2f(u.x), sh4.x); a.x = a.x > 0.f ? a.x : 0.f;
      a.y = fmaf(sc4.y, bf2f(u.y), sh4.y); a.y = a.y > 0.f ? a.y : 0.f;
      a.z = fmaf(sc4.z, bf2f(u.z), sh4.z); a.z = a.z > 0.f ? a.z : 0.f;
      a.w = fmaf(sc4.w, bf2f(u.w), sh4.w); a.w = a.w > 0.f ? a.w : 0.f;
    }
    *(float4*)&sZ[r][c] = a;
  }
  __syncthreads();
  float a2[4][2];
#pragma unroll
  for (int i=0;i<4;i++){ a2[i][0]=0.f; a2[i][1]=0.f; }
#pragma unroll 2
  for (int kb=0; kb<16; kb++){
    float4 zf[4];
    float2 wf[4];
#pragma unroll
    for (int i=0;i<4;i++) zf[i] = *(const float4*)&sZ[lr*4+i][kb*4];
#pragma unroll
    for (int kk=0;kk<4;kk++) wf[kk] = *(const float2*)&sW2[kb*4+kk][lc*2];
#pragma unroll
    for (int i=0;i<4;i++){
      a2[i][0] = fmaf(zf[i].x, wf[0].x, a2[i][0]);
      a2[i][1] = fmaf(zf[i].x, wf[0].y, a2[i][1]);
      a2[i][0] = fmaf(zf[i].y, wf[1].x, a2[i][0]);
      a2[i][1] = fmaf(zf[i].y, wf[1].y, a2[i][1]);
      a2[i][0] = fmaf(zf[i].z, wf[2].x, a2[i][0]);
      a2[i][1] = fmaf(zf[i].z, wf[2].y, a2[i][1]);
      a2[i][0] = fmaf(zf[i].w, wf[3].x, a2[i][0]);
      a2[i][1] = fmaf(zf[i].w, wf[3].y, a2[i][1]);
    }
  }
  float psum0=0.f, psum1=0.f, psq0=0.f, psq1=0.f;
#pragma unroll
  for (int i=0;i<4;i++){
    int row = rbase + lr*4 + i;
    if (row < P){
      float v0 = a2[i][0] + b2a;
      float v1 = a2[i][1] + b2b;
      *(float2*)&s2out[(size_t)row*32 + lc*2] = make_float2(v0, v1);
      psum0 += v0; psum1 += v1;
      psq0 += v0*v0; psq1 += v1*v1;
    }
  }
  __syncthreads();
  sred[lr][lc*2] = psum0; sred[lr][lc*2+1] = psum1;
  __syncthreads();
  if (tid < 32){
    float s = 0.f;
#pragma unroll
    for (int j=0;j<16;j++) s += sred[j][tid];
    atomicAdd(&gsum2[tid], s);
  }
  __syncthreads();
  sred[lr][lc*2] = psq0; sred[lr][lc*2+1] = psq1;
  __syncthreads();
  if (tid < 32){
    float s = 0.f;
#pragma unroll
    for (int j=0;j<16;j++) s += sred[j][tid];
    atomicAdd(&gsq2[tid], s);
  }
}

// ---------------- BN finalize ----------------
__global__ void bn_fin4_kernel(const float* __restrict__ stats,
    const float* __restrict__ g1, const float* __restrict__ be1, int l,
    float* __restrict__ scsh){
  int t = threadIdx.x;
  if (t >= 256) return;
  int gi = t>>6, c = t&63;
  float N = (gi==0) ? 1000.f : (gi==3) ? 20000.f : 200000.f;
  float invN = 1.f/N;
  float s = stats[gi*128 + c];
  float q = stats[gi*128 + 64 + c];
  float m = s*invN;
  float var = q*invN - m*m;
  float inv = rsqrtf(var + 1e-5f);
  float gg = g1[((size_t)l*4+gi)*64 + c];
  float bb = be1[((size_t)l*4+gi)*64 + c];
  float sc = gg*inv;
  scsh[gi*128 + c]      = sc;
  scsh[gi*128 + 64 + c] = bb - m*sc;
}

__global__ void bn_fin_kernel(const float* __restrict__ ssum, const float* __restrict__ ssq,
    const float* __restrict__ g, const float* __restrict__ be, float invN, int C,
    float* __restrict__ scsh){
  int c = threadIdx.x;
  if (c >= C) return;
  float m = ssum[c]*invN;
  float var = ssq[c]*invN - m*m;
  float inv = rsqrtf(var + 1e-5f);
  float s = g[c]*inv;
  scsh[c] = s; scsh[64+c] = be[c] - m*s;
}

// ---------------- final pass 3 ----------------
__global__ __launch_bounds__(256) void final_pass3_kernel(
    const float* __restrict__ s2, const float* __restrict__ Ws3, const float* __restrict__ bs3,
    const float* __restrict__ scsh2,
    float* __restrict__ outp, int P){
  __shared__ float w3[32], c2[32], h2[32];
  __shared__ float b3;
  if (threadIdx.x < 32){
    w3[threadIdx.x]=Ws3[threadIdx.x];
    c2[threadIdx.x]=scsh2[threadIdx.x];
    h2[threadIdx.x]=scsh2[64+threadIdx.x];
  }
  if (threadIdx.x == 0) b3 = bs3[0];
  __syncthreads();
  int r = blockIdx.x*blockDim.x + threadIdx.x;
  if (r >= P) return;
  float acc = b3;
  const float4* S4 = (const float4*)(s2 + (size_t)r*32);
#pragma unroll
  for (int k4=0;k4<8;k4++){
    float4 v = S4[k4];
    float a;
    a = c2[4*k4+0]*v.x + h2[4*k4+0]; acc += (a>0.f?a:0.f)*w3[4*k4+0];
    a = c2[4*k4+1]*v.y + h2[4*k4+1]; acc += (a>0.f?a:0.f)*w3[4*k4+1];
    a = c2[4*k4+2]*v.z + h2[4*k4+2]; acc += (a>0.f?a:0.f)*w3[4*k4+2];
    a = c2[4*k4+3]*v.w + h2[4*k4+3]; acc += (a>0.f?a:0.f)*w3[4*k4+3];
  }
  outp[r] = acc;
}

// ---------------- host ----------------
extern "C" void kernel_launch(void* const* d_in, const int* in_sizes, int n_in,
                              void* d_out, int out_size, void* d_ws, size_t ws_size,
                              hipStream_t stream){
  (void)in_sizes; (void)n_in; (void)out_size; (void)ws_size;
  const float* x_op   = (const float*)d_in[0];
  const float* x_ma   = (const float*)d_in[1];
  const float* x_jb   = (const float*)d_in[2];
  const float* Wenc_op= (const float*)d_in[3];
  const float* Wenc_ma= (const float*)d_in[4];
  const float* Wenc_jb= (const float*)d_in[5];
  const float* gW1_l0 = (const float*)d_in[6];
  const float* gW1_l12= (const float*)d_in[7];
  const float* gb1    = (const float*)d_in[8];
  const float* gg1    = (const float*)d_in[9];
  const float* gbe1   = (const float*)d_in[10];
  const float* gW2    = (const float*)d_in[11];
  const float* gb2    = (const float*)d_in[12];
  const float* geps   = (const float*)d_in[13];
  const float* Ws1    = (const float*)d_in[14];
  const float* bs1    = (const float*)d_in[15];
  const float* gs1    = (const float*)d_in[16];
  const float* bes1   = (const float*)d_in[17];
  const float* Ws2    = (const float*)d_in[18];
  const float* bs2    = (const float*)d_in[19];
  const float* gs2    = (const float*)d_in[20];
  const float* bes2   = (const float*)d_in[21];
  const float* Ws3    = (const float*)d_in[22];
  const float* bs3    = (const float*)d_in[23];
  const int* eom_s = (const int*)d_in[24];
  const int* eom_d = (const int*)d_in[25];
  const int* emo_s = (const int*)d_in[26];
  const int* emo_d = (const int*)d_in[27];
  const int* ejo_s = (const int*)d_in[28];
  const int* ejo_d = (const int*)d_in[29];
  const int* eoj_s = (const int*)d_in[30];
  const int* eoj_d = (const int*)d_in[31];
  const int* vpo = (const int*)d_in[32];
  const int* vpm = (const int*)d_in[33];
  const int* vpj = (const int*)d_in[34];
  float* outp = (float*)d_out;

  char* wsp = (char*)d_ws;
  auto alloc = [&](size_t bytes)->void*{
    void* p = (void*)wsp;
    wsp += (bytes + 255) & ~(size_t)255;
    return p;
  };
  float* P0 = (float*)alloc((size_t)N_OP_*64*4);
  float* P1 = (float*)alloc((size_t)N_OP_*64*4);
  float* P2 = (float*)alloc((size_t)N_OP_*64*4);
  float* J0 = (float*)alloc((size_t)N_JOB_*64*4);
  float* J1 = (float*)alloc((size_t)N_JOB_*64*4);
  float* M0 = (float*)alloc((size_t)N_MACH_*64*4);
  float* M1 = (float*)alloc((size_t)N_MACH_*64*4);
  float* S2 = (float*)alloc((size_t)N_PAIRS_*32*4);   // doubles as bf16 h1
  int* off_all  = (int*)alloc((size_t)(TOTC_+1)*4);
  int* cnt_all  = (int*)alloc((size_t)TOTC_*4);
  int* elist_all= (int*)alloc((size_t)E_TOT_*4);
  int* partials = (int*)alloc(1024*4);
  float* lstats = (float*)alloc(512*4);
  float* lscsh  = (float*)alloc(512*4);
  float* fstats = (float*)alloc(512*4);

  // -------- merged encode + CSR histogram (one dispatch; encode hides under hist latency) --------
  hipMemsetAsync(cnt_all, 0, (size_t)TOTC_*4, stream);
  const int GTOT = GH_ + G_OP_ + G_MA_ + G_JB_;   // 2037
  enc_hist_kernel<<<GTOT,256,0,stream>>>(
      x_op, Wenc_op, P0, x_ma, Wenc_ma, M0, x_jb, Wenc_jb, J0,
      eom_d, emo_d, ejo_d, eoj_d, cnt_all);
  const int NB = CDIV(TOTC_, 2048);   // 237
  scan_block_sums<<<NB,256,0,stream>>>(cnt_all, TOTC_, partials);
  scan_partials<<<1,256,0,stream>>>(partials, NB, off_all + TOTC_);
  scan_write_offsets<<<NB,256,0,stream>>>(cnt_all, TOTC_, partials, off_all);
  hipMemcpyAsync(cnt_all, off_all, (size_t)TOTC_*4, hipMemcpyDeviceToDevice, stream);
  fill_all_kernel<<<GH_,256,0,stream>>>(eom_s, eom_d, emo_s, emo_d,
                                        ejo_s, ejo_d, eoj_s, eoj_d,
                                        cnt_all, elist_all);

  float *Xop=P0, *Aop=P1, *Bop=P2;
  float *Xjb=J0, *Ajb=J1;
  float *Xma=M0, *Ama=M1;

  const int TA = CDIV(N_MACH_,64) + 2*CDIV(N_OP_,64) + CDIV(N_JOB_,64);  // 6579
  const int TB = CDIV(N_MACH_,64) + CDIV(N_OP_,64) + CDIV(N_JOB_,64);    // 3454

  for (int l=0; l<3; l++){
    int Din = (l==0) ? 32 : 64;
    hipMemsetAsync(lstats, 0, 512*4, stream);
    const float *W1m, *W1a, *W1b, *W1j;
    if (l==0){
      W1m = gW1_l0 + (size_t)0*32*64; W1a = gW1_l0 + (size_t)1*32*64;
      W1b = gW1_l0 + (size_t)2*32*64; W1j = gW1_l0 + (size_t)3*32*64;
    } else {
      W1m = gW1_l12 + ((size_t)(l-1)*4+0)*64*64; W1a = gW1_l12 + ((size_t)(l-1)*4+1)*64*64;
      W1b = gW1_l12 + ((size_t)(l-1)*4+2)*64*64; W1j = gW1_l12 + ((size_t)(l-1)*4+3)*64*64;
    }
    const float* b1m = gb1 + ((size_t)l*4+0)*64; const float* b1a = gb1 + ((size_t)l*4+1)*64;
    const float* b1b = gb1 + ((size_t)l*4+2)*64; const float* b1j = gb1 + ((size_t)l*4+3)*64;
    // machine aggregation (64 sub-buckets per machine; block per machine)
    agg_block_kernel<<<N_MACH_,256,0,stream>>>(off_all + B_OM_, elist_all, Xop, Ama, N_MACH_, Din);
    // fused gather(op/job) + partA GEMM (fp32)
    if (l==0){
      partA_fused_kernel<32><<<TA,256,0,stream>>>(
        off_all, elist_all, Xop, Xma, Xjb,
        Ama, Aop, Bop, Ajb,
        W1m, W1a, W1b, W1j, b1m, b1a, b1b, b1j,
        lstats, geps, 0);
    } else {
      partA_fused_kernel<64><<<TA,256,0,stream>>>(
        off_all, elist_all, Xop, Xma, Xjb,
        Ama, Aop, Bop, Ajb,
        W1m, W1a, W1b, W1j, b1m, b1a, b1b, b1j,
        lstats, geps, l*4);
    }
    bn_fin4_kernel<<<1,256,0,stream>>>(lstats, gg1, gbe1, l, lscsh);
    const float* W2m = gW2 + ((size_t)l*4+0)*64*64; const float* b2m = gb2 + ((size_t)l*4+0)*64;
    const float* W2a = gW2 + ((size_t)l*4+1)*64*64; const float* b2a = gb2 + ((size_t)l*4+1)*64;
    const float* W2b = gW2 + ((size_t)l*4+2)*64*64; const float* b2b = gb2 + ((size_t)l*4+2)*64;
    const float* W2j = gW2 + ((size_t)l*4+3)*64*64; const float* b2j = gb2 + ((size_t)l*4+3)*64;
    if (l==0){
      partB_batch_kernel<false><<<TB,256,0,stream>>>(
        Ama, Xma, W2m, b2m, lscsh+0,   N_MACH_,
        Aop, Bop, Xop, W2a, W2b, b2a, b2b, lscsh+128, lscsh+256, N_OP_,
        Ajb, Xjb, W2j, b2j, lscsh+384, N_JOB_);
    } else {
      partB_batch_kernel<true><<<TB,256,0,stream>>>(
        Ama, Xma, W2m, b2m, lscsh+0,   N_MACH_,
        Aop, Bop, Xop, W2a, W2b, b2a, b2b, lscsh+128, lscsh+256, N_OP_,
        Ajb, Xjb, W2j, b2j, lscsh+384, N_JOB_);
    }
    { float* t=Xma; Xma=Ama; Ama=t; }
    { float* t=Xop; Xop=Aop; Aop=t; }
    { float* t=Xjb; Xjb=Ajb; Ajb=t; }
  }

  // -------- final MLP over 500k gathered pairs --------
  float* fsum1 = fstats;       float* fsq1 = fstats+64;
  float* fsum2 = fstats+128;   float* fsq2 = fstats+192;
  float* scsh1 = fstats+256;
  float* scsh2 = fstats+384;
  unsigned short* H1BF = (unsigned short*)S2;
  hipMemsetAsync(fstats, 0, 256*4, stream);
  fp1_gemm_kernel<<<2048,256,0,stream>>>(Xop,Xma,Xjb,vpo,vpm,vpj,Ws1,bs1,H1BF,N_PAIRS_,fsum1,fsq1);
  bn_fin_kernel<<<1,64,0,stream>>>(fsum1,fsq1,gs1,bes1, 1.f/(float)N_PAIRS_, 64, scsh1);
  fp2_lite_kernel<<<CDIV(N_PAIRS_,64),256,0,stream>>>(scsh1, Ws2, bs2, H1BF, S2, N_PAIRS_, fsum2, fsq2);
  bn_fin_kernel<<<1,32,0,stream>>>(fsum2,fsq2,gs2,bes2, 1.f/(float)N_PAIRS_, 32, scsh2);
  final_pass3_kernel<<<CDIV(N_PAIRS_,256),256,0,stream>>>(S2, Ws3, bs3, scsh2, outp, N_PAIRS_);
}

// Round 18
// 1253.315 us; speedup vs baseline: 1.1087x; 1.0515x over previous
//
#include <hip/hip_runtime.h>
#include <math.h>

#define N_OP_   200000
#define N_MACH_ 1000
#define N_JOB_  20000
#define E_OM_   1000000
#define E_JO_   200000
#define N_PAIRS_ 500000

// merged CSR layout; om machines split into 64 sub-buckets each (atomic decontention)
#define B_OM_ 0
#define B_MO_ 64000
#define B_JO_ 264000
#define B_OJ_ 464000
#define TOTC_ 484000
#define E_TOT_ 2400000

// merged enc+hist dispatch partition
#define GH_   1172   // CDIV(E_TOT_/8, 256)
#define G_OP_ 782    // CDIV(N_OP_, 256)
#define G_MA_ 4      // CDIV(N_MACH_, 256)
#define G_JB_ 79     // CDIV(N_JOB_, 256)

#define CDIV(a,b) (((a)+(b)-1)/(b))

typedef __attribute__((ext_vector_type(8))) short short8v;   // 8 x bf16
typedef __attribute__((ext_vector_type(4))) float f32x4;

__device__ __forceinline__ unsigned short f2bf(float f){
  unsigned int u = __float_as_uint(f);
  return (unsigned short)((u + 0x7fffu + ((u>>16)&1u)) >> 16);
}
__device__ __forceinline__ float bf2f(unsigned short h){
  return __uint_as_float(((unsigned int)h)<<16);
}

// ---------------- encode body (device, compile-time DIN) ----------------
template<int DIN>
__device__ __forceinline__ void encode_body(const float* __restrict__ x,
    const float* __restrict__ W, float* __restrict__ out, int N, float* sW, int bid){
  if (threadIdx.x < DIN*16) sW[threadIdx.x] = W[threadIdx.x];
  __syncthreads();
  int i = bid*256 + threadIdx.x;
  if (i >= N) return;
  float xv[DIN];
#pragma unroll
  for (int k=0;k<DIN;k++) xv[k] = x[i*DIN+k];
#pragma unroll
  for (int j=0;j<16;j++){
    float h = 0.f;
#pragma unroll
    for (int k=0;k<DIN;k++) h = fmaf(xv[k], sW[k*16+j], h);
    float s, c;
    sincosf(h, &s, &c);
    out[(size_t)i*64 + j]      = s;
    out[(size_t)i*64 + 16 + j] = c;
  }
}

// ---------------- merged CSR helpers (om -> 64 sub-buckets/machine) ----------------
__device__ __forceinline__ int edge_cidx(int e,
    const int* __restrict__ eom_d, const int* __restrict__ emo_d,
    const int* __restrict__ ejo_d, const int* __restrict__ eoj_d){
  if (e < E_OM_)            return B_OM_ + eom_d[e]*64 + (e & 63);
  else if (e < 2*E_OM_)     return B_MO_ + emo_d[e - E_OM_];
  else if (e < 2*E_OM_+E_JO_) return B_JO_ + ejo_d[e - 2*E_OM_];
  else                      return B_OJ_ + eoj_d[e - 2*E_OM_ - E_JO_];
}
__device__ __forceinline__ int edge_src(int e,
    const int* __restrict__ eom_s, const int* __restrict__ emo_s,
    const int* __restrict__ ejo_s, const int* __restrict__ eoj_s){
  if (e < E_OM_)            return eom_s[e];
  else if (e < 2*E_OM_)     return emo_s[e - E_OM_];
  else if (e < 2*E_OM_+E_JO_) return ejo_s[e - 2*E_OM_];
  else                      return eoj_s[e - 2*E_OM_ - E_JO_];
}

// ---------------- merged encode + histogram (one dispatch; co-resident overlap) ----------------
__global__ __launch_bounds__(256) void enc_hist_kernel(
    const float* __restrict__ xop, const float* __restrict__ Wop, float* __restrict__ Pop,
    const float* __restrict__ xma, const float* __restrict__ Wma, float* __restrict__ Pma,
    const float* __restrict__ xjb, const float* __restrict__ Wjb, float* __restrict__ Pjb,
    const int* __restrict__ eom_d, const int* __restrict__ emo_d,
    const int* __restrict__ ejo_d, const int* __restrict__ eoj_d,
    int* __restrict__ cnt)
{
  __shared__ float sW[128];
  int b = blockIdx.x;
  if (b < GH_){
    const int gsz = GH_*256;
    int i0 = b*256 + threadIdx.x;
    for (int base = i0; base < E_TOT_; base += 8*gsz){
      int c[8]; bool act[8];
#pragma unroll
      for (int j=0;j<8;j++){
        int e = base + j*gsz;
        act[j] = (e < E_TOT_);
        if (act[j]) c[j] = edge_cidx(e, eom_d, emo_d, ejo_d, eoj_d);
      }
#pragma unroll
      for (int j=0;j<8;j++) if (act[j]) atomicAdd(&cnt[c[j]], 1);
    }
  } else if (b < GH_ + G_OP_){
    encode_body<8>(xop, Wop, Pop, N_OP_, sW, b - GH_);
  } else if (b < GH_ + G_OP_ + G_MA_){
    encode_body<4>(xma, Wma, Pma, N_MACH_, sW, b - GH_ - G_OP_);
  } else {
    encode_body<4>(xjb, Wjb, Pjb, N_JOB_, sW, b - GH_ - G_OP_ - G_MA_);
  }
}

__global__ __launch_bounds__(256) void fill_all_kernel(
    const int* __restrict__ eom_s, const int* __restrict__ eom_d,
    const int* __restrict__ emo_s, const int* __restrict__ emo_d,
    const int* __restrict__ ejo_s, const int* __restrict__ ejo_d,
    const int* __restrict__ eoj_s, const int* __restrict__ eoj_d,
    int* __restrict__ cursor, int* __restrict__ elist){
  int gsz = gridDim.x*blockDim.x;
  int i0 = blockIdx.x*blockDim.x + threadIdx.x;
  for (int base = i0; base < E_TOT_; base += 8*gsz){
    int cidx[8], src[8]; bool act[8];
#pragma unroll
    for (int j=0;j<8;j++){
      int e = base + j*gsz;
      act[j] = (e < E_TOT_);
      if (act[j]){
        cidx[j] = edge_cidx(e, eom_d, emo_d, ejo_d, eoj_d);
        src[j]  = edge_src (e, eom_s, emo_s, ejo_s, eoj_s);
      }
    }
    int p[8];
#pragma unroll
    for (int j=0;j<8;j++) if (act[j]) p[j] = atomicAdd(&cursor[cidx[j]], 1);
#pragma unroll
    for (int j=0;j<8;j++) if (act[j]) elist[p[j]] = src[j];
  }
}

// scan over 2048 elements per block (TOTC_=484000 -> NB=237 <= 256)
__global__ void scan_block_sums(const int* __restrict__ cnt, int N, int* __restrict__ partials){
  __shared__ int red[256];
  int base = blockIdx.x*2048;
  int s = 0;
#pragma unroll
  for (int j=0;j<8;j++){ int i = base + threadIdx.x + j*256; if (i<N) s += cnt[i]; }
  red[threadIdx.x] = s; __syncthreads();
  for (int st=128; st>0; st>>=1){ if (threadIdx.x<st) red[threadIdx.x]+=red[threadIdx.x+st]; __syncthreads(); }
  if (threadIdx.x==0) partials[blockIdx.x] = red[0];
}

__global__ void scan_partials(int* __restrict__ partials, int NB, int* __restrict__ offN){
  __shared__ int buf[256];
  int v = (threadIdx.x < NB) ? partials[threadIdx.x] : 0;
  buf[threadIdx.x] = v; __syncthreads();
  int acc = v;
  for (int st=1; st<256; st<<=1){
    int t = (threadIdx.x >= st) ? buf[threadIdx.x-st] : 0;
    __syncthreads();
    acc += t; buf[threadIdx.x] = acc;
    __syncthreads();
  }
  if (threadIdx.x < NB) partials[threadIdx.x] = acc - v;  // exclusive
  if (threadIdx.x == NB-1) offN[0] = acc;                 // total
}

// writes off AND a second copy (cursor) so no memcpy is needed before fill
__global__ void scan_write_offsets(const int* __restrict__ cnt, int N,
    const int* __restrict__ partials, int* __restrict__ off, int* __restrict__ cur){
  __shared__ int buf[256];
  int base = blockIdx.x*2048;
  int v[8]; int s = 0;
#pragma unroll
  for (int j=0;j<8;j++){ int i = base + threadIdx.x*8 + j; v[j] = (i<N)?cnt[i]:0; s += v[j]; }
  buf[threadIdx.x] = s; __syncthreads();
  int acc = s;
  for (int st=1; st<256; st<<=1){
    int t = (threadIdx.x >= st) ? buf[threadIdx.x-st] : 0;
    __syncthreads();
    acc += t; buf[threadIdx.x] = acc;
    __syncthreads();
  }
  int ex = partials[blockIdx.x] + acc - s;
#pragma unroll
  for (int j=0;j<8;j++){
    int i = base + threadIdx.x*8 + j;
    if (i<N){ off[i] = ex; cur[i] = ex; }
    ex += v[j];
  }
}

// ---------------- machine aggregation (64 sub-buckets per machine; block per machine) ----------------
__global__ __launch_bounds__(256) void agg_block_kernel(const int* __restrict__ off,
    const int* __restrict__ srcs, const float* __restrict__ feat,
    float* __restrict__ outp, int Ndst, int D){
  __shared__ float red[4][64];
  int m = blockIdx.x;
  if (m >= Ndst) return;
  int g = threadIdx.x >> 6, lane = threadIdx.x & 63;
  int s = off[m*64], e = off[m*64 + 64];
  float acc = 0.f;
  for (int base = s + g*64; base < e; base += 256){
    int cnt = e - base; if (cnt > 64) cnt = 64;
    int r = (lane < cnt) ? srcs[base + lane] : 0;
    int i = 0;
    for (; i + 4 <= cnt; i += 4){
      int r0 = __shfl(r, i), r1 = __shfl(r, i+1), r2 = __shfl(r, i+2), r3 = __shfl(r, i+3);
      float v0 = feat[(size_t)r0*64 + lane];
      float v1 = feat[(size_t)r1*64 + lane];
      float v2 = feat[(size_t)r2*64 + lane];
      float v3 = feat[(size_t)r3*64 + lane];
      acc += (v0 + v1) + (v2 + v3);
    }
    for (; i < cnt; i++){
      int ri = __shfl(r, i);
      acc += feat[(size_t)ri*64 + lane];
    }
  }
  red[g][lane] = acc;
  __syncthreads();
  if (g==0 && lane<D)
    outp[(size_t)m*64+lane] = red[0][lane]+red[1][lane]+red[2][lane]+red[3][lane];
}

// ---------------- shared tile helpers for partA ----------------
template<int K>
__device__ __forceinline__ void tile_gemm(const float* sW, const float* sZ,
    int lr, int lc, float acc[4][4]){
  constexpr int KP = K + 4;
#pragma unroll
  for (int i=0;i<4;i++){ acc[i][0]=0.f; acc[i][1]=0.f; acc[i][2]=0.f; acc[i][3]=0.f; }
#pragma unroll 2
  for (int kb = 0; kb < K/4; kb++){
    float4 zf[4], wf[4];
#pragma unroll
    for (int i=0;i<4;i++) zf[i] = *(const float4*)&sZ[(lr*4+i)*KP + kb*4];
#pragma unroll
    for (int kk=0;kk<4;kk++) wf[kk] = *(const float4*)&sW[(kb*4+kk)*64 + lc*4];
#pragma unroll
    for (int i=0;i<4;i++){
      acc[i][0] = fmaf(zf[i].x, wf[0].x, acc[i][0]);
      acc[i][1] = fmaf(zf[i].x, wf[0].y, acc[i][1]);
      acc[i][2] = fmaf(zf[i].x, wf[0].z, acc[i][2]);
      acc[i][3] = fmaf(zf[i].x, wf[0].w, acc[i][3]);
      acc[i][0] = fmaf(zf[i].y, wf[1].x, acc[i][0]);
      acc[i][1] = fmaf(zf[i].y, wf[1].y, acc[i][1]);
      acc[i][2] = fmaf(zf[i].y, wf[1].z, acc[i][2]);
      acc[i][3] = fmaf(zf[i].y, wf[1].w, acc[i][3]);
      acc[i][0] = fmaf(zf[i].z, wf[2].x, acc[i][0]);
      acc[i][1] = fmaf(zf[i].z, wf[2].y, acc[i][1]);
      acc[i][2] = fmaf(zf[i].z, wf[2].z, acc[i][2]);
      acc[i][3] = fmaf(zf[i].z, wf[2].w, acc[i][3]);
      acc[i][0] = fmaf(zf[i].w, wf[3].x, acc[i][0]);
      acc[i][1] = fmaf(zf[i].w, wf[3].y, acc[i][1]);
      acc[i][2] = fmaf(zf[i].w, wf[3].z, acc[i][2]);
      acc[i][3] = fmaf(zf[i].w, wf[3].w, acc[i][3]);
    }
  }
}

// epilogue + stats: writes z rows, accumulates per-column sums into st via sred
__device__ __forceinline__ void tile_epilogue_stats(float* z, const float* bias,
    float (*sred)[64], float* st, int rbase, int N, int lr, int lc, int tid,
    float acc[4][4]){
  float4 bias4 = *(const float4*)&bias[lc*4];
  float4 psum = make_float4(0.f,0.f,0.f,0.f), psq = make_float4(0.f,0.f,0.f,0.f);
#pragma unroll
  for (int i=0;i<4;i++){
    int row = rbase + lr*4 + i;
    if (row < N){
      float4 o;
      o.x = acc[i][0] + bias4.x;
      o.y = acc[i][1] + bias4.y;
      o.z = acc[i][2] + bias4.z;
      o.w = acc[i][3] + bias4.w;
      *(float4*)&z[(size_t)row*64 + lc*4] = o;
      psum.x += o.x; psum.y += o.y; psum.z += o.z; psum.w += o.w;
      psq.x += o.x*o.x; psq.y += o.y*o.y; psq.z += o.z*o.z; psq.w += o.w*o.w;
    }
  }
  __syncthreads();
  *(float4*)&sred[lr][lc*4] = psum;
  __syncthreads();
  if (tid < 64){
    float s = 0.f;
#pragma unroll
    for (int j=0;j<16;j++) s += sred[j][tid];
    atomicAdd(&st[tid], s);
  }
  __syncthreads();
  *(float4*)&sred[lr][lc*4] = psq;
  __syncthreads();
  if (tid < 64){
    float s = 0.f;
#pragma unroll
    for (int j=0;j<16;j++) s += sred[j][tid];
    atomicAdd(&st[64+tid], s);
  }
}

// ---------------- fused partA (fp32): seg mach reads pre-agg; op DUAL; job gather ----------------
template<int K>
__global__ __launch_bounds__(256,3) void partA_fused_kernel(
    const int* __restrict__ off_all, const int* __restrict__ elist,
    const float* __restrict__ Xop, const float* __restrict__ Xma, const float* __restrict__ Xjb,
    float* hm, float* hoA, float* hoB, float* hj,
    const float* __restrict__ Wm, const float* __restrict__ Wa,
    const float* __restrict__ Wb, const float* __restrict__ Wj,
    const float* __restrict__ bm, const float* __restrict__ ba,
    const float* __restrict__ bb, const float* __restrict__ bj,
    float* __restrict__ lstats,
    const float* __restrict__ epsp, int ebase)
{
  constexpr int KP = K + 4;
  constexpr int NF4 = K/16;
  __shared__ float sW[K*64];
  __shared__ float sZ[64*KP];
  __shared__ float sred[16][64];
  const int tid = threadIdx.x;
  const int lc = tid & 15, lr = tid >> 4;
  const int Tm = (N_MACH_+63)>>6, To = (N_OP_+63)>>6;
  int t = blockIdx.x;
  const int r = tid >> 2, q = tid & 3;
  const int cbase = q*(K/4);

  if (t < Tm || t >= Tm + To){
    // ---- single-segment path: machines (pre-agg) or jobs (gather) ----
    const bool mach = (t < Tm);
    const int tile = mach ? t : (t - Tm - To);
    float* z           = mach ? hm : hj;
    const float* x     = mach ? Xma : Xjb;
    const float* feat  = Xop;
    const float* W     = mach ? Wm : Wj;
    const float* b     = mach ? bm : bj;
    const int N        = mach ? N_MACH_ : N_JOB_;
    const int* offs    = off_all + (mach ? B_OM_ : B_OJ_);
    float* st          = lstats + (mach ? 0 : 3*128);
    const float e1 = 1.0f + epsp[ebase + (mach ? 0 : 3)];
    for (int idx = tid*4; idx < K*64; idx += 1024){
      *(float4*)&sW[idx] = *(const float4*)&W[(size_t)(idx>>6)*64 + (idx&63)];
    }
    const int rbase = tile << 6;
    {
      int row = rbase + r;
      float4 a4[NF4];
#pragma unroll
      for (int f=0; f<NF4; f++) a4[f] = make_float4(0.f,0.f,0.f,0.f);
      if (row < N){
        if (mach){
          const float4* H4 = (const float4*)&z[(size_t)row*64 + cbase];
#pragma unroll
          for (int f=0; f<NF4; f++) a4[f] = H4[f];
        } else {
          int s = offs[row], e = offs[row+1];
          int i = s;
          for (; i+2<=e; i+=2){
            int s0 = elist[i], s1 = elist[i+1];
            const float4* F0 = (const float4*)&feat[(size_t)s0*64 + cbase];
            const float4* F1 = (const float4*)&feat[(size_t)s1*64 + cbase];
#pragma unroll
            for (int f=0; f<NF4; f++){
              float4 v0=F0[f], v1=F1[f];
              a4[f].x += v0.x + v1.x; a4[f].y += v0.y + v1.y;
              a4[f].z += v0.z + v1.z; a4[f].w += v0.w + v1.w;
            }
          }
          if (i < e){
            int s0 = elist[i];
            const float4* F0 = (const float4*)&feat[(size_t)s0*64 + cbase];
#pragma unroll
            for (int f=0; f<NF4; f++){
              float4 v = F0[f];
              a4[f].x += v.x; a4[f].y += v.y; a4[f].z += v.z; a4[f].w += v.w;
            }
          }
        }
        const float4* X4 = (const float4*)&x[(size_t)row*64 + cbase];
#pragma unroll
        for (int f=0; f<NF4; f++){
          float4 xv = X4[f];
          a4[f].x = fmaf(e1, xv.x, a4[f].x);
          a4[f].y = fmaf(e1, xv.y, a4[f].y);
          a4[f].z = fmaf(e1, xv.z, a4[f].z);
          a4[f].w = fmaf(e1, xv.w, a4[f].w);
        }
      }
#pragma unroll
      for (int f=0; f<NF4; f++) *(float4*)&sZ[r*KP + cbase + f*4] = a4[f];
    }
    __syncthreads();
    float acc[4][4];
    tile_gemm<K>(sW, sZ, lr, lc, acc);
    tile_epilogue_stats(z, b, sred, st, rbase, N, lr, lc, tid, acc);
  } else {
    // ---- dual op path: GIN-A (mo CSR, Xma) then GIN-B (jo CSR, Xjb); shared Xop x-read ----
    const int tile = t - Tm;
    const int rbase = tile << 6;
    const int row = rbase + r;
    const float eA = 1.0f + epsp[ebase + 1];
    const float eB = 1.0f + epsp[ebase + 2];
    // shared x registers
    float4 xv4[NF4];
#pragma unroll
    for (int f=0; f<NF4; f++) xv4[f] = make_float4(0.f,0.f,0.f,0.f);
    if (row < N_OP_){
      const float4* X4 = (const float4*)&Xop[(size_t)row*64 + cbase];
#pragma unroll
      for (int f=0; f<NF4; f++) xv4[f] = X4[f];
    }
    // ---- pass A ----
    for (int idx = tid*4; idx < K*64; idx += 1024){
      *(float4*)&sW[idx] = *(const float4*)&Wa[(size_t)(idx>>6)*64 + (idx&63)];
    }
    {
      float4 a4[NF4];
#pragma unroll
      for (int f=0; f<NF4; f++) a4[f] = make_float4(0.f,0.f,0.f,0.f);
      if (row < N_OP_){
        const int* offs = off_all + B_MO_;
        int s = offs[row], e = offs[row+1];
        int i = s;
        for (; i+2<=e; i+=2){
          int s0 = elist[i], s1 = elist[i+1];
          const float4* F0 = (const float4*)&Xma[(size_t)s0*64 + cbase];
          const float4* F1 = (const float4*)&Xma[(size_t)s1*64 + cbase];
#pragma unroll
          for (int f=0; f<NF4; f++){
            float4 v0=F0[f], v1=F1[f];
            a4[f].x += v0.x + v1.x; a4[f].y += v0.y + v1.y;
            a4[f].z += v0.z + v1.z; a4[f].w += v0.w + v1.w;
          }
        }
        if (i < e){
          int s0 = elist[i];
          const float4* F0 = (const float4*)&Xma[(size_t)s0*64 + cbase];
#pragma unroll
          for (int f=0; f<NF4; f++){
            float4 v = F0[f];
            a4[f].x += v.x; a4[f].y += v.y; a4[f].z += v.z; a4[f].w += v.w;
          }
        }
#pragma unroll
        for (int f=0; f<NF4; f++){
          a4[f].x = fmaf(eA, xv4[f].x, a4[f].x);
          a4[f].y = fmaf(eA, xv4[f].y, a4[f].y);
          a4[f].z = fmaf(eA, xv4[f].z, a4[f].z);
          a4[f].w = fmaf(eA, xv4[f].w, a4[f].w);
        }
      }
#pragma unroll
      for (int f=0; f<NF4; f++) *(float4*)&sZ[r*KP + cbase + f*4] = a4[f];
    }
    __syncthreads();
    {
      float acc[4][4];
      tile_gemm<K>(sW, sZ, lr, lc, acc);
      tile_epilogue_stats(hoA, ba, sred, lstats + 128, rbase, N_OP_, lr, lc, tid, acc);
    }
    __syncthreads();   // all reads of sW/sZ done before restage
    // ---- pass B ----
    for (int idx = tid*4; idx < K*64; idx += 1024){
      *(float4*)&sW[idx] = *(const float4*)&Wb[(size_t)(idx>>6)*64 + (idx&63)];
    }
    {
      float4 a4[NF4];
#pragma unroll
      for (int f=0; f<NF4; f++) a4[f] = make_float4(0.f,0.f,0.f,0.f);
      if (row < N_OP_){
        const int* offs = off_all + B_JO_;
        int s = offs[row], e = offs[row+1];
        int i = s;
        for (; i+2<=e; i+=2){
          int s0 = elist[i], s1 = elist[i+1];
          const float4* F0 = (const float4*)&Xjb[(size_t)s0*64 + cbase];
          const float4* F1 = (const float4*)&Xjb[(size_t)s1*64 + cbase];
#pragma unroll
          for (int f=0; f<NF4; f++){
            float4 v0=F0[f], v1=F1[f];
            a4[f].x += v0.x + v1.x; a4[f].y += v0.y + v1.y;
            a4[f].z += v0.z + v1.z; a4[f].w += v0.w + v1.w;
          }
        }
        if (i < e){
          int s0 = elist[i];
          const float4* F0 = (const float4*)&Xjb[(size_t)s0*64 + cbase];
#pragma unroll
          for (int f=0; f<NF4; f++){
            float4 v = F0[f];
            a4[f].x += v.x; a4[f].y += v.y; a4[f].z += v.z; a4[f].w += v.w;
          }
        }
#pragma unroll
        for (int f=0; f<NF4; f++){
          a4[f].x = fmaf(eB, xv4[f].x, a4[f].x);
          a4[f].y = fmaf(eB, xv4[f].y, a4[f].y);
          a4[f].z = fmaf(eB, xv4[f].z, a4[f].z);
          a4[f].w = fmaf(eB, xv4[f].w, a4[f].w);
        }
      }
      __syncthreads();  // pass-A reductions done; safe to overwrite sZ
#pragma unroll
      for (int f=0; f<NF4; f++) *(float4*)&sZ[r*KP + cbase + f*4] = a4[f];
    }
    __syncthreads();
    {
      float acc[4][4];
      tile_gemm<K>(sW, sZ, lr, lc, acc);
      tile_epilogue_stats(hoB, bb, sred, lstats + 256, rbase, N_OP_, lr, lc, tid, acc);
    }
  }
}

// ---------------- batched partB (MFMA bf16): 3 segments (mach, op-dual, job) ----------------
template<bool RESID>
__global__ __launch_bounds__(256,3) void partB_batch_kernel(
    float* h0, const float* x0, const float* W20, const float* b20, const float* sc0, int N0,
    float* hA, const float* hBp, const float* x1, const float* W2a, const float* W2b,
    const float* b2a_, const float* b2b_, const float* scA, const float* scB, int N1,
    float* h3, const float* x3, const float* W23, const float* b23, const float* sc3, int N3)
{
  __shared__ unsigned short sA[64][72];   // bf16 activations, padded
  __shared__ unsigned short sB[64][72];   // bf16 W^T: sB[col][k]
  const int tid = threadIdx.x;
  const int lane = tid & 63, w = tid >> 6;
  const int lo = lane & 15, hi = lane >> 4;
  const int T0=(N0+63)>>6, T1=(N1+63)>>6;
  int t = blockIdx.x;
  int seg, tile;
  if (t < T0){ seg=0; tile=t; }
  else if (t < T0+T1){ seg=1; tile=t-T0; }
  else { seg=2; tile=t-T0-T1; }
  const int N = seg==0?N0:seg==1?N1:N3;
  float* hout = seg==0?h0:seg==1?hA:h3;
  const float* x = seg==0?x0:seg==1?x1:x3;
  const int rbase = tile << 6;
  const int nsrc = (seg==1) ? 2 : 1;
  f32x4 acc[4];
#pragma unroll
  for (int n=0;n<4;n++) acc[n] = (f32x4){0.f,0.f,0.f,0.f};
  for (int s=0; s<nsrc; s++){
    const float* hsrc = (seg==1) ? (s==0? (const float*)hA : hBp)
                                 : (seg==0? (const float*)h0 : (const float*)h3);
    const float* Wp   = (seg==1) ? (s==0? W2a : W2b) : (seg==0? W20 : W23);
    const float* scp  = (seg==1) ? (s==0? scA : scB) : (seg==0? sc0 : sc3);
    __syncthreads();
    // stage W^T (bf16): sB[c][k]
    for (int idx = tid; idx < 1024; idx += 256){
      int k = idx >> 4, c4 = (idx & 15)*4;
      float4 wv = *(const float4*)&Wp[(size_t)k*64 + c4];
      sB[c4+0][k] = f2bf(wv.x);
      sB[c4+1][k] = f2bf(wv.y);
      sB[c4+2][k] = f2bf(wv.z);
      sB[c4+3][k] = f2bf(wv.w);
    }
    // stage A = relu(BN(h)) (bf16)
    for (int idx = tid; idx < 1024; idx += 256){
      int r = idx >> 4, c4 = (idx & 15)*4;
      int row = rbase + r;
      ushort4 zz = make_ushort4(0,0,0,0);
      if (row < N){
        float4 hv = *(const float4*)&hsrc[(size_t)row*64 + c4];
        float4 sc4 = *(const float4*)&scp[c4];
        float4 sh4 = *(const float4*)&scp[64 + c4];
        float a0 = fmaf(sc4.x, hv.x, sh4.x); a0 = a0>0.f?a0:0.f;
        float a1 = fmaf(sc4.y, hv.y, sh4.y); a1 = a1>0.f?a1:0.f;
        float a2 = fmaf(sc4.z, hv.z, sh4.z); a2 = a2>0.f?a2:0.f;
        float a3 = fmaf(sc4.w, hv.w, sh4.w); a3 = a3>0.f?a3:0.f;
        zz = make_ushort4(f2bf(a0), f2bf(a1), f2bf(a2), f2bf(a3));
      }
      *(ushort4*)&sA[r][c4] = zz;
    }
    __syncthreads();
    short8v af0 = *(const short8v*)&sA[w*16 + lo][hi*8];
    short8v af1 = *(const short8v*)&sA[w*16 + lo][32 + hi*8];
#pragma unroll
    for (int n=0;n<4;n++){
      short8v bf0 = *(const short8v*)&sB[n*16 + lo][hi*8];
      short8v bf1 = *(const short8v*)&sB[n*16 + lo][32 + hi*8];
      acc[n] = __builtin_amdgcn_mfma_f32_16x16x32_bf16(af0, bf0, acc[n], 0, 0, 0);
      acc[n] = __builtin_amdgcn_mfma_f32_16x16x32_bf16(af1, bf1, acc[n], 0, 0, 0);
    }
  }
  // epilogue: bias (+resid) + store. D mapping: col = lo (+16n), row = hi*4 + j.
#pragma unroll
  for (int n=0;n<4;n++){
    int col = n*16 + lo;
    float bv;
    if (seg==1) bv = b2a_[col] + b2b_[col];
    else if (seg==0) bv = b20[col];
    else bv = b23[col];
#pragma unroll
    for (int j=0;j<4;j++){
      int row = rbase + w*16 + hi*4 + j;
      if (row < N){
        float v = acc[n][j] + bv;
        if (RESID) v += x[(size_t)row*64 + col];
        hout[(size_t)row*64 + col] = v;
      }
    }
  }
}

// ---------------- fp1 (MFMA bf16): gather-GEMM (K=192) -> h1 bf16 + stats ----------------
__global__ __launch_bounds__(256,3) void fp1_gemm_kernel(
    const float* __restrict__ Xop, const float* __restrict__ Xma, const float* __restrict__ Xjb,
    const int* __restrict__ vpo, const int* __restrict__ vpm, const int* __restrict__ vpj,
    const float* __restrict__ Ws1, const float* __restrict__ bs1,
    unsigned short* __restrict__ h1bf,
    int P, float* __restrict__ gsum, float* __restrict__ gsq)
{
  __shared__ unsigned short sA[64][72];
  __shared__ unsigned short sB[64][72];
  __shared__ float sred[16][64];
  const int tid = threadIdx.x;
  const int lane = tid & 63, w = tid >> 6;
  const int lo = lane & 15, hi = lane >> 4;
  float ps[4] = {0.f,0.f,0.f,0.f};
  float pq[4] = {0.f,0.f,0.f,0.f};
  const int ntiles = (P + 63) >> 6;
  for (int t = blockIdx.x; t < ntiles; t += gridDim.x){
    const int rbase = t << 6;
    f32x4 acc[4];
#pragma unroll
    for (int n=0;n<4;n++) acc[n] = (f32x4){0.f,0.f,0.f,0.f};
    for (int s=0; s<3; s++){
      const int* vps = (s==0) ? vpo : (s==1) ? vpm : vpj;
      const float* Xs = (s==0) ? Xop : (s==1) ? Xma : Xjb;
      __syncthreads();
      // stage W chunk transposed (bf16)
      for (int idx = tid; idx < 1024; idx += 256){
        int k = idx >> 4, c4 = (idx & 15)*4;
        float4 wv = *(const float4*)&Ws1[(size_t)(s*64 + k)*64 + c4];
        sB[c4+0][k] = f2bf(wv.x);
        sB[c4+1][k] = f2bf(wv.y);
        sB[c4+2][k] = f2bf(wv.z);
        sB[c4+3][k] = f2bf(wv.w);
      }
      // stage gathered features (bf16)
      for (int idx = tid; idx < 1024; idx += 256){
        int r = idx >> 4, c4 = (idx & 15)*4;
        int row = rbase + r;
        ushort4 zz = make_ushort4(0,0,0,0);
        if (row < P){
          int nd = vps[row];
          float4 z = *(const float4*)&Xs[(size_t)nd*64 + c4];
          zz = make_ushort4(f2bf(z.x), f2bf(z.y), f2bf(z.z), f2bf(z.w));
        }
        *(ushort4*)&sA[r][c4] = zz;
      }
      __syncthreads();
      short8v af0 = *(const short8v*)&sA[w*16 + lo][hi*8];
      short8v af1 = *(const short8v*)&sA[w*16 + lo][32 + hi*8];
#pragma unroll
      for (int n=0;n<4;n++){
        short8v bf0 = *(const short8v*)&sB[n*16 + lo][hi*8];
        short8v bf1 = *(const short8v*)&sB[n*16 + lo][32 + hi*8];
        acc[n] = __builtin_amdgcn_mfma_f32_16x16x32_bf16(af0, bf0, acc[n], 0, 0, 0);
        acc[n] = __builtin_amdgcn_mfma_f32_16x16x32_bf16(af1, bf1, acc[n], 0, 0, 0);
      }
    }
    // epilogue: bias + store bf16 + stats
#pragma unroll
    for (int n=0;n<4;n++){
      int col = n*16 + lo;
      float bv = bs1[col];
#pragma unroll
      for (int j=0;j<4;j++){
        int row = rbase + w*16 + hi*4 + j;
        if (row < P){
          float v = acc[n][j] + bv;
          h1bf[(size_t)row*64 + col] = f2bf(v);
          ps[n] += v; pq[n] += v*v;
        }
      }
    }
  }
  // block reduction of per-lane column partials
  __syncthreads();
#pragma unroll
  for (int n=0;n<4;n++) sred[w*4 + hi][n*16 + lo] = ps[n];
  __syncthreads();
  if (tid < 64){
    float s = 0.f;
#pragma unroll
    for (int j=0;j<16;j++) s += sred[j][tid];
    atomicAdd(&gsum[tid], s);
  }
  __syncthreads();
#pragma unroll
  for (int n=0;n<4;n++) sred[w*4 + hi][n*16 + lo] = pq[n];
  __syncthreads();
  if (tid < 64){
    float s = 0.f;
#pragma unroll
    for (int j=0;j<16;j++) s += sred[j][tid];
    atomicAdd(&gsq[tid], s);
  }
}

// ---------------- fp2_lite: read bf16 h1, BN+ReLU, @Ws2+bs2 -> s2 (in place) + stats2 ----------------
__global__ __launch_bounds__(256,3) void fp2_lite_kernel(
    const float* __restrict__ scsh1,
    const float* __restrict__ Ws2, const float* __restrict__ bs2,
    const unsigned short* __restrict__ h1bf,
    float* __restrict__ s2out, int P,
    float* __restrict__ gsum2, float* __restrict__ gsq2)
{
  __shared__ float sZ[64][68];
  __shared__ float sW2[64][32];
  __shared__ float sred[16][64];
  const int tid = threadIdx.x;
  const int lc = tid & 15, lr = tid >> 4;
  for (int idx = tid*4; idx < 2048; idx += 1024){
    int k = idx >> 5, c = idx & 31;
    *(float4*)&sW2[k][c] = *(const float4*)&Ws2[(size_t)k*32 + c];
  }
  const float b2a = bs2[lc*2], b2b = bs2[lc*2+1];
  const int rbase = blockIdx.x << 6;
  for (int idx = tid*4; idx < 4096; idx += 1024){
    int r = idx >> 6, c = idx & 63;
    int row = rbase + r;
    float4 a = make_float4(0.f,0.f,0.f,0.f);
    if (row < P){
      ushort4 u = *(const ushort4*)&h1bf[(size_t)row*64 + c];
      float4 sc4 = *(const float4*)&scsh1[c];
      float4 sh4 = *(const float4*)&scsh1[64 + c];
      a.x = fmaf(sc4.x, bf2f(u.x), sh4.x); a.x = a.x > 0.f ? a.x : 0.f;
      a.y = fmaf(sc4.y, bf2f(u.y), sh4.y); a.y = a.y > 0.f ? a.y : 0.f;
      a.z = fmaf(sc4.z, bf2f(u.z), sh4.z); a.z = a.z > 0.f ? a.z : 0.f;
      a.w = fmaf(sc4.w, bf2f(u.w), sh4.w); a.w = a.w > 0.f ? a.w : 0.f;
    }
    *(float4*)&sZ[r][c] = a;
  }
  __syncthreads();
  float a2[4][2];
#pragma unroll
  for (int i=0;i<4;i++){ a2[i][0]=0.f; a2[i][1]=0.f; }
#pragma unroll 2
  for (int kb=0; kb<16; kb++){
    float4 zf[4];
    float2 wf[4];
#pragma unroll
    for (int i=0;i<4;i++) zf[i] = *(const float4*)&sZ[lr*4+i][kb*4];
#pragma unroll
    for (int kk=0;kk<4;kk++) wf[kk] = *(const float2*)&sW2[kb*4+kk][lc*2];
#pragma unroll
    for (int i=0;i<4;i++){
      a2[i][0] = fmaf(zf[i].x, wf[0].x, a2[i][0]);
      a2[i][1] = fmaf(zf[i].x, wf[0].y, a2[i][1]);
      a2[i][0] = fmaf(zf[i].y, wf[1].x, a2[i][0]);
      a2[i][1] = fmaf(zf[i].y, wf[1].y, a2[i][1]);
      a2[i][0] = fmaf(zf[i].z, wf[2].x, a2[i][0]);
      a2[i][1] = fmaf(zf[i].z, wf[2].y, a2[i][1]);
      a2[i][0] = fmaf(zf[i].w, wf[3].x, a2[i][0]);
      a2[i][1] = fmaf(zf[i].w, wf[3].y, a2[i][1]);
    }
  }
  float psum0=0.f, psum1=0.f, psq0=0.f, psq1=0.f;
#pragma unroll
  for (int i=0;i<4;i++){
    int row = rbase + lr*4 + i;
    if (row < P){
      float v0 = a2[i][0] + b2a;
      float v1 = a2[i][1] + b2b;
      *(float2*)&s2out[(size_t)row*32 + lc*2] = make_float2(v0, v1);
      psum0 += v0; psum1 += v1;
      psq0 += v0*v0; psq1 += v1*v1;
    }
  }
  __syncthreads();
  sred[lr][lc*2] = psum0; sred[lr][lc*2+1] = psum1;
  __syncthreads();
  if (tid < 32){
    float s = 0.f;
#pragma unroll
    for (int j=0;j<16;j++) s += sred[j][tid];
    atomicAdd(&gsum2[tid], s);
  }
  __syncthreads();
  sred[lr][lc*2] = psq0; sred[lr][lc*2+1] = psq1;
  __syncthreads();
  if (tid < 32){
    float s = 0.f;
#pragma unroll
    for (int j=0;j<16;j++) s += sred[j][tid];
    atomicAdd(&gsq2[tid], s);
  }
}

// ---------------- BN finalize ----------------
__global__ void bn_fin4_kernel(const float* __restrict__ stats,
    const float* __restrict__ g1, const float* __restrict__ be1, int l,
    float* __restrict__ scsh){
  int t = threadIdx.x;
  if (t >= 256) return;
  int gi = t>>6, c = t&63;
  float N = (gi==0) ? 1000.f : (gi==3) ? 20000.f : 200000.f;
  float invN = 1.f/N;
  float s = stats[gi*128 + c];
  float q = stats[gi*128 + 64 + c];
  float m = s*invN;
  float var = q*invN - m*m;
  float inv = rsqrtf(var + 1e-5f);
  float gg = g1[((size_t)l*4+gi)*64 + c];
  float bb = be1[((size_t)l*4+gi)*64 + c];
  float sc = gg*inv;
  scsh[gi*128 + c]      = sc;
  scsh[gi*128 + 64 + c] = bb - m*sc;
}

__global__ void bn_fin_kernel(const float* __restrict__ ssum, const float* __restrict__ ssq,
    const float* __restrict__ g, const float* __restrict__ be, float invN, int C,
    float* __restrict__ scsh){
  int c = threadIdx.x;
  if (c >= C) return;
  float m = ssum[c]*invN;
  float var = ssq[c]*invN - m*m;
  float inv = rsqrtf(var + 1e-5f);
  float s = g[c]*inv;
  scsh[c] = s; scsh[64+c] = be[c] - m*s;
}

// ---------------- final pass 3 ----------------
__global__ __launch_bounds__(256) void final_pass3_kernel(
    const float* __restrict__ s2, const float* __restrict__ Ws3, const float* __restrict__ bs3,
    const float* __restrict__ scsh2,
    float* __restrict__ outp, int P){
  __shared__ float w3[32], c2[32], h2[32];
  __shared__ float b3;
  if (threadIdx.x < 32){
    w3[threadIdx.x]=Ws3[threadIdx.x];
    c2[threadIdx.x]=scsh2[threadIdx.x];
    h2[threadIdx.x]=scsh2[64+threadIdx.x];
  }
  if (threadIdx.x == 0) b3 = bs3[0];
  __syncthreads();
  int r = blockIdx.x*blockDim.x + threadIdx.x;
  if (r >= P) return;
  float acc = b3;
  const float4* S4 = (const float4*)(s2 + (size_t)r*32);
#pragma unroll
  for (int k4=0;k4<8;k4++){
    float4 v = S4[k4];
    float a;
    a = c2[4*k4+0]*v.x + h2[4*k4+0]; acc += (a>0.f?a:0.f)*w3[4*k4+0];
    a = c2[4*k4+1]*v.y + h2[4*k4+1]; acc += (a>0.f?a:0.f)*w3[4*k4+1];
    a = c2[4*k4+2]*v.z + h2[4*k4+2]; acc += (a>0.f?a:0.f)*w3[4*k4+2];
    a = c2[4*k4+3]*v.w + h2[4*k4+3]; acc += (a>0.f?a:0.f)*w3[4*k4+3];
  }
  outp[r] = acc;
}

// ---------------- host ----------------
extern "C" void kernel_launch(void* const* d_in, const int* in_sizes, int n_in,
                              void* d_out, int out_size, void* d_ws, size_t ws_size,
                              hipStream_t stream){
  (void)in_sizes; (void)n_in; (void)out_size; (void)ws_size;
  const float* x_op   = (const float*)d_in[0];
  const float* x_ma   = (const float*)d_in[1];
  const float* x_jb   = (const float*)d_in[2];
  const float* Wenc_op= (const float*)d_in[3];
  const float* Wenc_ma= (const float*)d_in[4];
  const float* Wenc_jb= (const float*)d_in[5];
  const float* gW1_l0 = (const float*)d_in[6];
  const float* gW1_l12= (const float*)d_in[7];
  const float* gb1    = (const float*)d_in[8];
  const float* gg1    = (const float*)d_in[9];
  const float* gbe1   = (const float*)d_in[10];
  const float* gW2    = (const float*)d_in[11];
  const float* gb2    = (const float*)d_in[12];
  const float* geps   = (const float*)d_in[13];
  const float* Ws1    = (const float*)d_in[14];
  const float* bs1    = (const float*)d_in[15];
  const float* gs1    = (const float*)d_in[16];
  const float* bes1   = (const float*)d_in[17];
  const float* Ws2    = (const float*)d_in[18];
  const float* bs2    = (const float*)d_in[19];
  const float* gs2    = (const float*)d_in[20];
  const float* bes2   = (const float*)d_in[21];
  const float* Ws3    = (const float*)d_in[22];
  const float* bs3    = (const float*)d_in[23];
  const int* eom_s = (const int*)d_in[24];
  const int* eom_d = (const int*)d_in[25];
  const int* emo_s = (const int*)d_in[26];
  const int* emo_d = (const int*)d_in[27];
  const int* ejo_s = (const int*)d_in[28];
  const int* ejo_d = (const int*)d_in[29];
  const int* eoj_s = (const int*)d_in[30];
  const int* eoj_d = (const int*)d_in[31];
  const int* vpo = (const int*)d_in[32];
  const int* vpm = (const int*)d_in[33];
  const int* vpj = (const int*)d_in[34];
  float* outp = (float*)d_out;

  char* wsp = (char*)d_ws;
  auto alloc = [&](size_t bytes)->void*{
    void* p = (void*)wsp;
    wsp += (bytes + 255) & ~(size_t)255;
    return p;
  };
  float* P0 = (float*)alloc((size_t)N_OP_*64*4);
  float* P1 = (float*)alloc((size_t)N_OP_*64*4);
  float* P2 = (float*)alloc((size_t)N_OP_*64*4);
  float* J0 = (float*)alloc((size_t)N_JOB_*64*4);
  float* J1 = (float*)alloc((size_t)N_JOB_*64*4);
  float* M0 = (float*)alloc((size_t)N_MACH_*64*4);
  float* M1 = (float*)alloc((size_t)N_MACH_*64*4);
  float* S2 = (float*)alloc((size_t)N_PAIRS_*32*4);   // doubles as bf16 h1
  int* off_all  = (int*)alloc((size_t)(TOTC_+1)*4);
  int* cnt_all  = (int*)alloc((size_t)TOTC_*4);
  int* elist_all= (int*)alloc((size_t)E_TOT_*4);
  int* partials = (int*)alloc(1024*4);
  float* lstats = (float*)alloc(512*4);
  float* lscsh  = (float*)alloc(512*4);
  float* fstats = (float*)alloc(512*4);

  // -------- merged encode + CSR histogram (one dispatch; encode hides under hist latency) --------
  hipMemsetAsync(cnt_all, 0, (size_t)TOTC_*4, stream);
  const int GTOT = GH_ + G_OP_ + G_MA_ + G_JB_;   // 2037
  enc_hist_kernel<<<GTOT,256,0,stream>>>(
      x_op, Wenc_op, P0, x_ma, Wenc_ma, M0, x_jb, Wenc_jb, J0,
      eom_d, emo_d, ejo_d, eoj_d, cnt_all);
  const int NB = CDIV(TOTC_, 2048);   // 237
  scan_block_sums<<<NB,256,0,stream>>>(cnt_all, TOTC_, partials);
  scan_partials<<<1,256,0,stream>>>(partials, NB, off_all + TOTC_);
  scan_write_offsets<<<NB,256,0,stream>>>(cnt_all, TOTC_, partials, off_all, cnt_all);
  fill_all_kernel<<<GH_,256,0,stream>>>(eom_s, eom_d, emo_s, emo_d,
                                        ejo_s, ejo_d, eoj_s, eoj_d,
                                        cnt_all, elist_all);

  float *Xop=P0, *Aop=P1, *Bop=P2;
  float *Xjb=J0, *Ajb=J1;
  float *Xma=M0, *Ama=M1;

  const int TA = CDIV(N_MACH_,64) + CDIV(N_OP_,64) + CDIV(N_JOB_,64);   // 3454 (op dual)
  const int TB = CDIV(N_MACH_,64) + CDIV(N_OP_,64) + CDIV(N_JOB_,64);   // 3454

  for (int l=0; l<3; l++){
    int Din = (l==0) ? 32 : 64;
    hipMemsetAsync(lstats, 0, 512*4, stream);
    const float *W1m, *W1a, *W1b, *W1j;
    if (l==0){
      W1m = gW1_l0 + (size_t)0*32*64; W1a = gW1_l0 + (size_t)1*32*64;
      W1b = gW1_l0 + (size_t)2*32*64; W1j = gW1_l0 + (size_t)3*32*64;
    } else {
      W1m = gW1_l12 + ((size_t)(l-1)*4+0)*64*64; W1a = gW1_l12 + ((size_t)(l-1)*4+1)*64*64;
      W1b = gW1_l12 + ((size_t)(l-1)*4+2)*64*64; W1j = gW1_l12 + ((size_t)(l-1)*4+3)*64*64;
    }
    const float* b1m = gb1 + ((size_t)l*4+0)*64; const float* b1a = gb1 + ((size_t)l*4+1)*64;
    const float* b1b = gb1 + ((size_t)l*4+2)*64; const float* b1j = gb1 + ((size_t)l*4+3)*64;
    // machine aggregation (64 sub-buckets per machine; block per machine)
    agg_block_kernel<<<N_MACH_,256,0,stream>>>(off_all + B_OM_, elist_all, Xop, Ama, N_MACH_, Din);
    // fused gather + partA GEMM (fp32; op segments merged into dual blocks)
    if (l==0){
      partA_fused_kernel<32><<<TA,256,0,stream>>>(
        off_all, elist_all, Xop, Xma, Xjb,
        Ama, Aop, Bop, Ajb,
        W1m, W1a, W1b, W1j, b1m, b1a, b1b, b1j,
        lstats, geps, 0);
    } else {
      partA_fused_kernel<64><<<TA,256,0,stream>>>(
        off_all, elist_all, Xop, Xma, Xjb,
        Ama, Aop, Bop, Ajb,
        W1m, W1a, W1b, W1j, b1m, b1a, b1b, b1j,
        lstats, geps, l*4);
    }
    bn_fin4_kernel<<<1,256,0,stream>>>(lstats, gg1, gbe1, l, lscsh);
    const float* W2m = gW2 + ((size_t)l*4+0)*64*64; const float* b2m = gb2 + ((size_t)l*4+0)*64;
    const float* W2a = gW2 + ((size_t)l*4+1)*64*64; const float* b2a = gb2 + ((size_t)l*4+1)*64;
    const float* W2b = gW2 + ((size_t)l*4+2)*64*64; const float* b2b = gb2 + ((size_t)l*4+2)*64;
    const float* W2j = gW2 + ((size_t)l*4+3)*64*64; const float* b2j = gb2 + ((size_t)l*4+3)*64;
    if (l==0){
      partB_batch_kernel<false><<<TB,256,0,stream>>>(
        Ama, Xma, W2m, b2m, lscsh+0,   N_MACH_,
        Aop, Bop, Xop, W2a, W2b, b2a, b2b, lscsh+128, lscsh+256, N_OP_,
        Ajb, Xjb, W2j, b2j, lscsh+384, N_JOB_);
    } else {
      partB_batch_kernel<true><<<TB,256,0,stream>>>(
        Ama, Xma, W2m, b2m, lscsh+0,   N_MACH_,
        Aop, Bop, Xop, W2a, W2b, b2a, b2b, lscsh+128, lscsh+256, N_OP_,
        Ajb, Xjb, W2j, b2j, lscsh+384, N_JOB_);
    }
    { float* t=Xma; Xma=Ama; Ama=t; }
    { float* t=Xop; Xop=Aop; Aop=t; }
    { float* t=Xjb; Xjb=Ajb; Ajb=t; }
  }

  // -------- final MLP over 500k gathered pairs --------
  float* fsum1 = fstats;       float* fsq1 = fstats+64;
  float* fsum2 = fstats+128;   float* fsq2 = fstats+192;
  float* scsh1 = fstats+256;
  float* scsh2 = fstats+384;
  unsigned short* H1BF = (unsigned short*)S2;
  hipMemsetAsync(fstats, 0, 256*4, stream);
  fp1_gemm_kernel<<<2048,256,0,stream>>>(Xop,Xma,Xjb,vpo,vpm,vpj,Ws1,bs1,H1BF,N_PAIRS_,fsum1,fsq1);
  bn_fin_kernel<<<1,64,0,stream>>>(fsum1,fsq1,gs1,bes1, 1.f/(float)N_PAIRS_, 64, scsh1);
  fp2_lite_kernel<<<CDIV(N_PAIRS_,64),256,0,stream>>>(scsh1, Ws2, bs2, H1BF, S2, N_PAIRS_, fsum2, fsq2);
  bn_fin_kernel<<<1,32,0,stream>>>(fsum2,fsq2,gs2,bes2, 1.f/(float)N_PAIRS_, 32, scsh2);
  final_pass3_kernel<<<CDIV(N_PAIRS_,256),256,0,stream>>>(S2, Ws3, bs3, scsh2, outp, N_PAIRS_);
}